// Round 2
// 1007.469 us; speedup vs baseline: 1.1617x; 1.1617x over previous
//
#include <hip/hip_runtime.h>

#define HD 128

constexpr int N_ATOMS = 20000;
constexpr int N_EDGES = 320000;
constexpr int NLAY   = 4;
constexpr int NMOL   = 200;
constexpr float FCUT  = 5.0f;
constexpr float DELTA = FCUT / 127.0f;
constexpr float GCOEFF = -0.5f / (DELTA * DELTA);
constexpr float PI_F  = 3.14159265358979323846f;
constexpr float LN2F  = 0.6931471805599453f;

typedef unsigned short u16;
typedef __attribute__((ext_vector_type(8))) short short8v;
typedef __attribute__((ext_vector_type(4))) float f32x4;

__device__ __forceinline__ float sspf(float x) {
  return fmaxf(x, 0.0f) + log1pf(expf(-fabsf(x))) - LN2F;
}
__device__ __forceinline__ float sigmf(float x) {
  return 1.0f / (1.0f + expf(-x));
}

// bf16 pack/unpack (round-to-nearest-even)
__device__ __forceinline__ unsigned bfpack(float a, float b) {
  unsigned ua = __float_as_uint(a);
  unsigned ub = __float_as_uint(b);
  ua = (ua + 0x7FFFu + ((ua >> 16) & 1u)) >> 16;
  ub = (ub + 0x7FFFu + ((ub >> 16) & 1u)) >> 16;
  return (ub << 16) | ua;
}
__device__ __forceinline__ float bflo(unsigned p) { return __uint_as_float(p << 16); }
__device__ __forceinline__ float bfhi(unsigned p) { return __uint_as_float(p & 0xFFFF0000u); }
__device__ __forceinline__ u16 f2bf(float x) {
  unsigned u = __float_as_uint(x);
  u = (u + 0x7FFFu + ((u >> 16) & 1u)) >> 16;
  return (u16)u;
}
__device__ __forceinline__ float bf2f(u16 b) { return __uint_as_float((unsigned)b << 16); }

// ------------------------------------------------------------------
// small elementwise kernels
// ------------------------------------------------------------------

__global__ __launch_bounds__(256) void geom_k(
    const float* __restrict__ pos, const int* __restrict__ row,
    const int* __restrict__ col, float* __restrict__ dist)
{
  int e = blockIdx.x * 256 + threadIdx.x;
  if (e >= N_EDGES) return;
  int r = row[e], c = col[e];
  float dx = pos[3*r+0] - pos[3*c+0];
  float dy = pos[3*r+1] - pos[3*c+1];
  float dz = pos[3*r+2] - pos[3*c+2];
  dist[e] = sqrtf(dx*dx + dy*dy + dz*dz);
}

__global__ __launch_bounds__(256) void h0_k(
    const float* __restrict__ emb, const int* __restrict__ z,
    float* __restrict__ h0)
{
  int i = blockIdx.x * 256 + threadIdx.x;
  if (i >= N_ATOMS * HD) return;
  int n = i >> 7, k = i & 127;
  h0[i] = emb[z[n] * HD + k];
}

// bf16 weight prep: wp = bf16(W) row-major, wt = bf16(W^T)
__global__ __launch_bounds__(256) void wprep_k(
    const float* __restrict__ l1, const float* __restrict__ l2,
    const float* __restrict__ bw, u16* __restrict__ wt, u16* __restrict__ wp)
{
  int i = blockIdx.x * 256 + threadIdx.x;
  if (i >= NLAY * 3 * HD * HD) return;
  int e = i & (HD * HD - 1);
  int wl = i >> 14;          // lay*3 + wsel
  int wsel = wl % 3;
  int lay = wl / 3;
  const float* W = (wsel == 0 ? l1 : (wsel == 1 ? l2 : bw)) + (size_t)lay * HD * HD;
  u16 b = f2bf(W[e]);
  int k = e >> 7, n = e & 127;
  size_t base = (size_t)wl << 14;
  wp[base + e] = b;
  wt[base + (size_t)n * HD + k] = b;
}

// ------------------------------------------------------------------
// CSR build: histogram, scan, scatter
// ------------------------------------------------------------------
__global__ __launch_bounds__(256) void hist_k(
    const int* __restrict__ idx, int* __restrict__ cnt)
{
  int e = blockIdx.x * 256 + threadIdx.x;
  if (e >= N_EDGES) return;
  atomicAdd(&cnt[idx[e]], 1);
}

__global__ __launch_bounds__(256) void scan_k(
    const int* __restrict__ cnt, int* __restrict__ ptr)
{
  constexpr int CH = 79;  // 256*79 = 20224 >= 20001
  __shared__ int part[256];
  int t = threadIdx.x;
  int base = t * CH;
  int s = 0;
  for (int i = 0; i < CH; i++) {
    int idx = base + i;
    if (idx < N_ATOMS) s += cnt[idx];
  }
  part[t] = s;
  __syncthreads();
  for (int off = 1; off < 256; off <<= 1) {
    int u = (t >= off) ? part[t - off] : 0;
    __syncthreads();
    part[t] += u;
    __syncthreads();
  }
  int run = part[t] - s;
  for (int i = 0; i < CH; i++) {
    int idx = base + i;
    if (idx > N_ATOMS) break;
    ptr[idx] = run;
    if (idx < N_ATOMS) run += cnt[idx];
  }
}

__global__ __launch_bounds__(256) void scat_row_k(
    const int* __restrict__ row, const int* __restrict__ col,
    const float* __restrict__ dist, int* __restrict__ cur,
    int* __restrict__ rother, float* __restrict__ rdist,
    int* __restrict__ slotof)
{
  int e = blockIdx.x * 256 + threadIdx.x;
  if (e >= N_EDGES) return;
  int p = atomicAdd(&cur[row[e]], 1);
  rother[p] = col[e];
  rdist[p] = dist[e];
  slotof[e] = p;
}

__global__ __launch_bounds__(256) void scat_col_k(
    const int* __restrict__ row, const int* __restrict__ col,
    const float* __restrict__ dist, int* __restrict__ cur,
    int* __restrict__ cother, float* __restrict__ cdist,
    const int* __restrict__ slotof, int* __restrict__ cslot)
{
  int e = blockIdx.x * 256 + threadIdx.x;
  if (e >= N_EDGES) return;
  int p = atomicAdd(&cur[col[e]], 1);
  cother[p] = row[e];
  cdist[p] = dist[e];
  cslot[p] = slotof[e];
}

// ------------------------------------------------------------------
// table build
// ------------------------------------------------------------------
__global__ __launch_bounds__(256) void nodeA_k(
    float* __restrict__ A, float* __restrict__ dA, int nnode, float hstep)
{
  int i = blockIdx.x * 256 + threadIdx.x;
  if (i >= nnode * HD) return;
  int node = i >> 7, g = i & 127;
  float d = (float)node * hstep;
  float t = d - (float)g * DELTA;
  float a = expf(GCOEFF * t * t);
  A[i] = a;
  dA[i] = a * 2.0f * GCOEFF * t;
}

__global__ __launch_bounds__(256) void nodeact_k(
    const float* __restrict__ t1, const float* __restrict__ u,
    float* __restrict__ s, float* __restrict__ sp, int total)
{
  int i = blockIdx.x * 256 + threadIdx.x;
  if (i >= total) return;
  float x = t1[i];
  s[i] = sspf(x);
  sp[i] = sigmf(x) * u[i];
}

__global__ __launch_bounds__(256) void nodecomb_k(
    const float* __restrict__ P0, const float* __restrict__ D0,
    unsigned* __restrict__ T, int nnode, float hstep)
{
  int i = blockIdx.x * 256 + threadIdx.x;
  int total = NLAY * nnode * HD;
  if (i >= total) return;
  int rem = i % (nnode * HD);
  int node = rem >> 7;
  float d = (float)node * hstep;
  float C  = 0.5f * cosf(d * (PI_F / FCUT)) + 0.5f;
  float Cp = -0.5f * sinf(d * (PI_F / FCUT)) * (PI_F / FCUT);
  float p = P0[i], q = D0[i];
  T[i] = bfpack(p * C, q * C + p * Cp);
}

// batched (over blockIdx.y = layer) plain fp32 GEMM for table build
__global__ __launch_bounds__(256) void gemm128b_k(
    const float* __restrict__ A, size_t astride,
    const float* __restrict__ B, size_t bstride,
    const float* __restrict__ bias, size_t biasstride,
    float* __restrict__ C, size_t cstride, int M)
{
  int l = blockIdx.y;
  A += (size_t)l * astride;
  B += (size_t)l * bstride;
  if (bias) bias += (size_t)l * biasstride;
  C += (size_t)l * cstride;

  __shared__ float As[16][68];
  __shared__ float Bs[16][132];
  int t = threadIdx.x;
  int tx = t & 15, ty = t >> 4;
  int m0 = blockIdx.x * 64;

  float acc[4][8];
#pragma unroll
  for (int r = 0; r < 4; r++)
#pragma unroll
    for (int c = 0; c < 8; c++) acc[r][c] = 0.0f;

  for (int k0 = 0; k0 < HD; k0 += 16) {
    {
      int rrow = t >> 2;
      int kg = (t & 3) * 4;
      int gm = m0 + rrow;
      float4 av = make_float4(0.f, 0.f, 0.f, 0.f);
      if (gm < M) av = *(const float4*)(A + (size_t)gm * HD + k0 + kg);
      As[kg+0][rrow] = av.x; As[kg+1][rrow] = av.y;
      As[kg+2][rrow] = av.z; As[kg+3][rrow] = av.w;
    }
#pragma unroll
    for (int it = 0; it < 2; it++) {
      int f4 = t + it * 256;
      int kk = f4 >> 5;
      int n4 = (f4 & 31) * 4;
      float4 bv = *(const float4*)(B + (size_t)(k0 + kk) * HD + n4);
      *(float4*)&Bs[kk][n4] = bv;
    }
    __syncthreads();
#pragma unroll
    for (int kk = 0; kk < 16; kk++) {
      float a[4], b[8];
#pragma unroll
      for (int r = 0; r < 4; r++) a[r] = As[kk][ty * 4 + r];
#pragma unroll
      for (int c = 0; c < 8; c++) b[c] = Bs[kk][tx * 8 + c];
#pragma unroll
      for (int r = 0; r < 4; r++)
#pragma unroll
        for (int c = 0; c < 8; c++) acc[r][c] = fmaf(a[r], b[c], acc[r][c]);
    }
    __syncthreads();
  }

  int n0 = tx * 8;
  float bv[8];
#pragma unroll
  for (int c = 0; c < 8; c++) bv[c] = bias ? bias[n0 + c] : 0.0f;
#pragma unroll
  for (int r = 0; r < 4; r++) {
    int gm = m0 + ty * 4 + r;
    if (gm >= M) continue;
    float out[8];
#pragma unroll
    for (int c = 0; c < 8; c++) out[c] = acc[r][c] + bv[c];
    *(float4*)(C + (size_t)gm * HD + n0)     = *(float4*)&out[0];
    *(float4*)(C + (size_t)gm * HD + n0 + 4) = *(float4*)&out[4];
  }
}

// ------------------------------------------------------------------
// MFMA GEMM core: 64-row tile, 4 waves; wave = 32 rows x 64 cols.
// A is fp32, split hi/lo bf16 into LDS (fp32-accurate product).
// B fragments (bf16, Barr[n][k] = B[k][n]) live in VGPRs, loaded from L2.
// mfma_f32_16x16x32_bf16: A lane l -> row l&15, k (l>>4)*8..+8 (contig);
//                         C/D lane l -> col l&15, row (l>>4)*4 + reg.
// ------------------------------------------------------------------

__device__ __forceinline__ void load_bfrag(const u16* __restrict__ B,
    int wc, int lc, int lg, short8v bf[4][4])
{
#pragma unroll
  for (int ks = 0; ks < 4; ++ks)
#pragma unroll
    for (int nt = 0; nt < 4; ++nt)
      bf[ks][nt] = *(const short8v*)(B + (size_t)(wc*64 + nt*16 + lc) * HD + ks*32 + lg*8);
}

__device__ __forceinline__ void stage_A(const float* __restrict__ A, int M, int m0, int t,
    u16 (*__restrict__ Ah)[136], u16 (*__restrict__ Al)[136])
{
#pragma unroll
  for (int it = 0; it < 4; ++it) {
    int idx = it * 256 + t;
    int r = idx >> 4;
    int kg = (idx & 15) << 3;
    int gm = m0 + r;
    float f[8];
    if (gm < M) {
      float4 v0 = *(const float4*)(A + (size_t)gm * HD + kg);
      float4 v1 = *(const float4*)(A + (size_t)gm * HD + kg + 4);
      f[0]=v0.x; f[1]=v0.y; f[2]=v0.z; f[3]=v0.w;
      f[4]=v1.x; f[5]=v1.y; f[6]=v1.z; f[7]=v1.w;
    } else {
#pragma unroll
      for (int j = 0; j < 8; j++) f[j] = 0.f;
    }
    unsigned hi[4], lo[4];
#pragma unroll
    for (int j = 0; j < 4; j++) {
      hi[j] = bfpack(f[2*j], f[2*j+1]);
      float r0 = f[2*j]   - bflo(hi[j]);
      float r1 = f[2*j+1] - bfhi(hi[j]);
      lo[j] = bfpack(r0, r1);
    }
    *(uint4*)&Ah[r][kg] = make_uint4(hi[0], hi[1], hi[2], hi[3]);
    *(uint4*)&Al[r][kg] = make_uint4(lo[0], lo[1], lo[2], lo[3]);
  }
}

__device__ __forceinline__ void mfma_compute(const u16 (*__restrict__ Ah)[136],
    const u16 (*__restrict__ Al)[136], const short8v bf[4][4],
    int wr, int lc, int lg, f32x4 acc[2][4])
{
#pragma unroll
  for (int ks = 0; ks < 4; ++ks) {
    short8v ah[2], al[2];
#pragma unroll
    for (int mt = 0; mt < 2; ++mt) {
      int rrow = wr*32 + mt*16 + lc;
      ah[mt] = *(const short8v*)&Ah[rrow][ks*32 + lg*8];
      al[mt] = *(const short8v*)&Al[rrow][ks*32 + lg*8];
    }
#pragma unroll
    for (int mt = 0; mt < 2; ++mt)
#pragma unroll
      for (int nt = 0; nt < 4; ++nt) {
        acc[mt][nt] = __builtin_amdgcn_mfma_f32_16x16x32_bf16(ah[mt], bf[ks][nt], acc[mt][nt], 0, 0, 0);
        acc[mt][nt] = __builtin_amdgcn_mfma_f32_16x16x32_bf16(al[mt], bf[ks][nt], acc[mt][nt], 0, 0, 0);
      }
  }
}

// hx = h @ W  (Bt = W^T bf16), output bf16 rows of 128 u16
__global__ __launch_bounds__(256) void mm_hx_k(
    const float* __restrict__ h, const u16* __restrict__ Bt,
    u16* __restrict__ hx, int M)
{
  __shared__ u16 Ah[64][136], Al[64][136];
  int t = threadIdx.x;
  int lane = t & 63, wave = t >> 6;
  int wr = wave >> 1, wc = wave & 1;
  int lc = lane & 15, lg = lane >> 4;
  int m0 = blockIdx.x * 64;

  short8v bf[4][4];
  load_bfrag(Bt, wc, lc, lg, bf);
  stage_A(h, M, m0, t, Ah, Al);
  __syncthreads();

  f32x4 z = {0.f, 0.f, 0.f, 0.f};
  f32x4 acc[2][4];
#pragma unroll
  for (int mt = 0; mt < 2; mt++)
#pragma unroll
    for (int nt = 0; nt < 4; nt++) acc[mt][nt] = z;
  mfma_compute(Ah, Al, bf, wr, lc, lg, acc);

#pragma unroll
  for (int mt = 0; mt < 2; ++mt)
#pragma unroll
    for (int nt = 0; nt < 4; ++nt) {
      int ccol = wc*64 + nt*16 + lc;
#pragma unroll
      for (int j = 0; j < 4; j++) {
        int grow = m0 + wr*32 + mt*16 + lg*4 + j;
        if (grow < M) hx[(size_t)grow * HD + ccol] = f2bf(acc[mt][nt][j]);
      }
    }
}

// C = A @ W^T + addin  (Bp = W bf16 row-major), fp32 out
__global__ __launch_bounds__(256) void mm_bwdT_k(
    const float* __restrict__ A, const u16* __restrict__ Bp,
    const float* __restrict__ addin, float* __restrict__ C, int M)
{
  __shared__ u16 Ah[64][136], Al[64][136];
  int t = threadIdx.x;
  int lane = t & 63, wave = t >> 6;
  int wr = wave >> 1, wc = wave & 1;
  int lc = lane & 15, lg = lane >> 4;
  int m0 = blockIdx.x * 64;

  short8v bf[4][4];
  load_bfrag(Bp, wc, lc, lg, bf);
  stage_A(A, M, m0, t, Ah, Al);
  __syncthreads();

  f32x4 z = {0.f, 0.f, 0.f, 0.f};
  f32x4 acc[2][4];
#pragma unroll
  for (int mt = 0; mt < 2; mt++)
#pragma unroll
    for (int nt = 0; nt < 4; nt++) acc[mt][nt] = z;
  mfma_compute(Ah, Al, bf, wr, lc, lg, acc);

#pragma unroll
  for (int mt = 0; mt < 2; ++mt)
#pragma unroll
    for (int nt = 0; nt < 4; ++nt) {
      int ccol = wc*64 + nt*16 + lc;
#pragma unroll
      for (int j = 0; j < 4; j++) {
        int grow = m0 + wr*32 + mt*16 + lg*4 + j;
        if (grow < M)
          C[(size_t)grow * HD + ccol] = acc[mt][nt][j] + addin[(size_t)grow * HD + ccol];
      }
    }
}

// fused fwd tail: V = agg@l2 + l2b (store fp32), h' = h + ssp(V)@bw + bb
__global__ __launch_bounds__(256) void ftail_mfma_k(
    const float* __restrict__ agg, const u16* __restrict__ l2t,
    const float* __restrict__ l2b, const u16* __restrict__ bwt,
    const float* __restrict__ bb, const float* __restrict__ h,
    float* __restrict__ vbuf, float* __restrict__ hout, int M)
{
  __shared__ u16 Ah[64][136], Al[64][136];
  int t = threadIdx.x;
  int lane = t & 63, wave = t >> 6;
  int wr = wave >> 1, wc = wave & 1;
  int lc = lane & 15, lg = lane >> 4;
  int m0 = blockIdx.x * 64;

  short8v bf[4][4];
  load_bfrag(l2t, wc, lc, lg, bf);
  stage_A(agg, M, m0, t, Ah, Al);
  __syncthreads();

  f32x4 z = {0.f, 0.f, 0.f, 0.f};
  f32x4 acc[2][4];
#pragma unroll
  for (int mt = 0; mt < 2; mt++)
#pragma unroll
    for (int nt = 0; nt < 4; nt++) acc[mt][nt] = z;
  mfma_compute(Ah, Al, bf, wr, lc, lg, acc);
  __syncthreads();   // all waves done reading A before S overwrites LDS

  // epilogue1: V store + S = ssp(V) split hi/lo back into the A tiles
#pragma unroll
  for (int mt = 0; mt < 2; ++mt)
#pragma unroll
    for (int nt = 0; nt < 4; ++nt) {
      int ccol = wc*64 + nt*16 + lc;
      float bv = l2b[ccol];
#pragma unroll
      for (int j = 0; j < 4; j++) {
        int lrow = wr*32 + mt*16 + lg*4 + j;
        int grow = m0 + lrow;
        float x = acc[mt][nt][j] + bv;
        if (grow < M) vbuf[(size_t)grow * HD + ccol] = x;
        float s = sspf(x);
        u16 shi = f2bf(s);
        Ah[lrow][ccol] = shi;
        Al[lrow][ccol] = f2bf(s - bf2f(shi));
      }
    }
  load_bfrag(bwt, wc, lc, lg, bf);   // global-only, no LDS hazard
  __syncthreads();                   // S tiles complete before GEMM2 reads

#pragma unroll
  for (int mt = 0; mt < 2; mt++)
#pragma unroll
    for (int nt = 0; nt < 4; nt++) acc[mt][nt] = z;
  mfma_compute(Ah, Al, bf, wr, lc, lg, acc);

#pragma unroll
  for (int mt = 0; mt < 2; ++mt)
#pragma unroll
    for (int nt = 0; nt < 4; ++nt) {
      int ccol = wc*64 + nt*16 + lc;
      float bv = bb[ccol];
#pragma unroll
      for (int j = 0; j < 4; j++) {
        int grow = m0 + wr*32 + mt*16 + lg*4 + j;
        if (grow < M)
          hout[(size_t)grow * HD + ccol] =
              acc[mt][nt][j] + bv + h[(size_t)grow * HD + ccol];
      }
    }
}

// fused bwd head: dv = (g@bw^T)*sigm(v), dagg = dv@l2^T (bf16 out)
__global__ __launch_bounds__(256) void bhead_mfma_k(
    const float* __restrict__ g, const u16* __restrict__ bwp,
    const float* __restrict__ v, const u16* __restrict__ l2p,
    u16* __restrict__ dagg, int M)
{
  __shared__ u16 Ah[64][136], Al[64][136];
  int t = threadIdx.x;
  int lane = t & 63, wave = t >> 6;
  int wr = wave >> 1, wc = wave & 1;
  int lc = lane & 15, lg = lane >> 4;
  int m0 = blockIdx.x * 64;

  short8v bf[4][4];
  load_bfrag(bwp, wc, lc, lg, bf);
  stage_A(g, M, m0, t, Ah, Al);
  __syncthreads();

  f32x4 z = {0.f, 0.f, 0.f, 0.f};
  f32x4 acc[2][4];
#pragma unroll
  for (int mt = 0; mt < 2; mt++)
#pragma unroll
    for (int nt = 0; nt < 4; nt++) acc[mt][nt] = z;
  mfma_compute(Ah, Al, bf, wr, lc, lg, acc);
  __syncthreads();

  // dv = acc * sigm(v), split hi/lo into the A tiles
#pragma unroll
  for (int mt = 0; mt < 2; ++mt)
#pragma unroll
    for (int nt = 0; nt < 4; ++nt) {
      int ccol = wc*64 + nt*16 + lc;
#pragma unroll
      for (int j = 0; j < 4; j++) {
        int lrow = wr*32 + mt*16 + lg*4 + j;
        int grow = m0 + lrow;
        float vv = (grow < M) ? v[(size_t)grow * HD + ccol] : 0.f;
        float dv = acc[mt][nt][j] * sigmf(vv);
        u16 dhi = f2bf(dv);
        Ah[lrow][ccol] = dhi;
        Al[lrow][ccol] = f2bf(dv - bf2f(dhi));
      }
    }
  load_bfrag(l2p, wc, lc, lg, bf);
  __syncthreads();

#pragma unroll
  for (int mt = 0; mt < 2; mt++)
#pragma unroll
    for (int nt = 0; nt < 4; nt++) acc[mt][nt] = z;
  mfma_compute(Ah, Al, bf, wr, lc, lg, acc);

#pragma unroll
  for (int mt = 0; mt < 2; ++mt)
#pragma unroll
    for (int nt = 0; nt < 4; ++nt) {
      int ccol = wc*64 + nt*16 + lc;
#pragma unroll
      for (int j = 0; j < 4; j++) {
        int grow = m0 + wr*32 + mt*16 + lg*4 + j;
        if (grow < M) dagg[(size_t)grow * HD + ccol] = f2bf(acc[mt][nt][j]);
      }
    }
}

// ------------------------------------------------------------------
// forward gather: agg[a] = sum_in hx[src] * P(d); bf16 table + hx
// ------------------------------------------------------------------
__global__ __launch_bounds__(256) void gath_fwd_k(
    const int* __restrict__ cptr, const int* __restrict__ cother,
    const float* __restrict__ cdist, const unsigned* __restrict__ T,
    const unsigned* __restrict__ hx, float* __restrict__ agg,
    float inv_h, float hstep)
{
  int a = blockIdx.x * 4 + (threadIdx.x >> 6);
  if (a >= N_ATOMS) return;
  int half = (threadIdx.x >> 5) & 1;
  int l32 = threadIdx.x & 31;
  int ch = l32 * 4;
  int beg = cptr[a], end = cptr[a + 1];
  float s0 = 0.f, s1 = 0.f, s2 = 0.f, s3 = 0.f;
  for (int j = beg + half; j < end; j += 2) {
    int other = cother[j];
    float d = cdist[j];
    float fi = d * inv_h;
    int i0 = (int)fi;
    float t = fi - (float)i0;
    float t2 = t * t, t3 = t2 * t;
    float a00 = 2.f*t3 - 3.f*t2 + 1.f;
    float a10 = (t3 - 2.f*t2 + t) * hstep;
    float a01 = 3.f*t2 - 2.f*t3;
    float a11 = (t3 - t2) * hstep;
    const unsigned* tp = T + (size_t)i0 * HD + ch;
    uint4 q0 = *(const uint4*)(tp);
    uint4 q1 = *(const uint4*)(tp + HD);
    uint2 hp = *(const uint2*)(hx + (size_t)other * 64 + l32 * 2);
    float v0 = a00*bflo(q0.x) + a10*bfhi(q0.x) + a01*bflo(q1.x) + a11*bfhi(q1.x);
    float v1 = a00*bflo(q0.y) + a10*bfhi(q0.y) + a01*bflo(q1.y) + a11*bfhi(q1.y);
    float v2 = a00*bflo(q0.z) + a10*bfhi(q0.z) + a01*bflo(q1.z) + a11*bfhi(q1.z);
    float v3 = a00*bflo(q0.w) + a10*bfhi(q0.w) + a01*bflo(q1.w) + a11*bfhi(q1.w);
    s0 = fmaf(bflo(hp.x), v0, s0);
    s1 = fmaf(bfhi(hp.x), v1, s1);
    s2 = fmaf(bflo(hp.y), v2, s2);
    s3 = fmaf(bfhi(hp.y), v3, s3);
  }
  s0 += __shfl_xor(s0, 32, 64);
  s1 += __shfl_xor(s1, 32, 64);
  s2 += __shfl_xor(s2, 32, 64);
  s3 += __shfl_xor(s3, 32, 64);
  if (half == 0)
    *(float4*)(agg + (size_t)a * HD + ch) = make_float4(s0, s1, s2, s3);
}

// ------------------------------------------------------------------
// backward gather
// ------------------------------------------------------------------
__global__ __launch_bounds__(256) void gath_bwd_k(
    const int* __restrict__ rptr, const int* __restrict__ rother,
    const float* __restrict__ rdist, const unsigned* __restrict__ T,
    const unsigned* __restrict__ dagg, const unsigned* __restrict__ hx,
    float* __restrict__ dhx, float* __restrict__ ddslot,
    float inv_h, float hstep)
{
  int a = blockIdx.x * 4 + (threadIdx.x >> 6);
  if (a >= N_ATOMS) return;
  int half = (threadIdx.x >> 5) & 1;
  int l32 = threadIdx.x & 31;
  int ch = l32 * 4;
  int beg = rptr[a], end = rptr[a + 1];
  uint2 hp = *(const uint2*)(hx + (size_t)a * 64 + l32 * 2);
  float h0 = bflo(hp.x), h1 = bfhi(hp.x), h2 = bflo(hp.y), h3 = bfhi(hp.y);
  float s0 = 0.f, s1 = 0.f, s2 = 0.f, s3 = 0.f;
  for (int j = beg + half; j < end; j += 2) {
    int other = rother[j];
    float d = rdist[j];
    float fi = d * inv_h;
    int i0 = (int)fi;
    float t = fi - (float)i0;
    float t2 = t * t, t3 = t2 * t;
    float a00 = 2.f*t3 - 3.f*t2 + 1.f;
    float a10 = (t3 - 2.f*t2 + t) * hstep;
    float a01 = 3.f*t2 - 2.f*t3;
    float a11 = (t3 - t2) * hstep;
    float b00 = (6.f*t2 - 6.f*t) * inv_h;
    float b10 = 3.f*t2 - 4.f*t + 1.f;
    float b01 = -b00;
    float b11 = 3.f*t2 - 2.f*t;
    const unsigned* tp = T + (size_t)i0 * HD + ch;
    uint4 q0 = *(const uint4*)(tp);
    uint4 q1 = *(const uint4*)(tp + HD);
    uint2 dp = *(const uint2*)(dagg + (size_t)other * 64 + l32 * 2);
    float da0 = bflo(dp.x), da1 = bfhi(dp.x), da2 = bflo(dp.y), da3 = bfhi(dp.y);
    float v0 = a00*bflo(q0.x) + a10*bfhi(q0.x) + a01*bflo(q1.x) + a11*bfhi(q1.x);
    float v1 = a00*bflo(q0.y) + a10*bfhi(q0.y) + a01*bflo(q1.y) + a11*bfhi(q1.y);
    float v2 = a00*bflo(q0.z) + a10*bfhi(q0.z) + a01*bflo(q1.z) + a11*bfhi(q1.z);
    float v3 = a00*bflo(q0.w) + a10*bfhi(q0.w) + a01*bflo(q1.w) + a11*bfhi(q1.w);
    float g0 = b00*bflo(q0.x) + b10*bfhi(q0.x) + b01*bflo(q1.x) + b11*bfhi(q1.x);
    float g1 = b00*bflo(q0.y) + b10*bfhi(q0.y) + b01*bflo(q1.y) + b11*bfhi(q1.y);
    float g2 = b00*bflo(q0.z) + b10*bfhi(q0.z) + b01*bflo(q1.z) + b11*bfhi(q1.z);
    float g3 = b00*bflo(q0.w) + b10*bfhi(q0.w) + b01*bflo(q1.w) + b11*bfhi(q1.w);
    s0 = fmaf(da0, v0, s0);
    s1 = fmaf(da1, v1, s1);
    s2 = fmaf(da2, v2, s2);
    s3 = fmaf(da3, v3, s3);
    float dot = da0*h0*g0 + da1*h1*g1 + da2*h2*g2 + da3*h3*g3;
#pragma unroll
    for (int off = 16; off > 0; off >>= 1) dot += __shfl_down(dot, off, 32);
    if (l32 == 0) ddslot[j] += dot;
  }
  s0 += __shfl_xor(s0, 32, 64);
  s1 += __shfl_xor(s1, 32, 64);
  s2 += __shfl_xor(s2, 32, 64);
  s3 += __shfl_xor(s3, 32, 64);
  if (half == 0)
    *(float4*)(dhx + (size_t)a * HD + ch) = make_float4(s0, s1, s2, s3);
}

// ------------------------------------------------------------------
// fused head: s = h4@hw1 + hb1; ea[a] = ssp(s)@hw2 + hb2;
// gh = (sigm(s)*hw2) @ hw1^T
// ------------------------------------------------------------------
__global__ __launch_bounds__(256) void headf_k(
    const float* __restrict__ h4, const float* __restrict__ hw1,
    const float* __restrict__ hb1, const float* __restrict__ hw2,
    const float* __restrict__ hb2, float* __restrict__ ea,
    float* __restrict__ gh)
{
  __shared__ float As[16][68];
  __shared__ float Bs[16][132];
  __shared__ float Ss[64][68];
  __shared__ float red[64][17];
  int t = threadIdx.x;
  int tx = t & 15, ty = t >> 4;
  int m0 = blockIdx.x * 64;

  float acc4[4][4];
#pragma unroll
  for (int r = 0; r < 4; r++)
#pragma unroll
    for (int c = 0; c < 4; c++) acc4[r][c] = 0.0f;

  for (int k0 = 0; k0 < HD; k0 += 16) {
    {
      int rrow = t >> 2;
      int kg = (t & 3) * 4;
      int gm = m0 + rrow;
      float4 av = make_float4(0.f, 0.f, 0.f, 0.f);
      if (gm < N_ATOMS) av = *(const float4*)(h4 + (size_t)gm * HD + k0 + kg);
      As[kg+0][rrow] = av.x; As[kg+1][rrow] = av.y;
      As[kg+2][rrow] = av.z; As[kg+3][rrow] = av.w;
    }
    if (t < 256) {
      int kk = t >> 4;
      int n4 = (t & 15) * 4;
      float4 bv = *(const float4*)(hw1 + (size_t)(k0 + kk) * 64 + n4);
      *(float4*)&Bs[kk][n4] = bv;
    }
    __syncthreads();
#pragma unroll
    for (int kk = 0; kk < 16; kk++) {
      float a[4], b[4];
#pragma unroll
      for (int r = 0; r < 4; r++) a[r] = As[kk][ty * 4 + r];
#pragma unroll
      for (int c = 0; c < 4; c++) b[c] = Bs[kk][tx * 4 + c];
#pragma unroll
      for (int r = 0; r < 4; r++)
#pragma unroll
        for (int c = 0; c < 4; c++) acc4[r][c] = fmaf(a[r], b[c], acc4[r][c]);
    }
    __syncthreads();
  }

  {
    int n0 = tx * 4;
    float b1v[4], w2v[4];
#pragma unroll
    for (int c = 0; c < 4; c++) { b1v[c] = hb1[n0 + c]; w2v[c] = hw2[n0 + c]; }
#pragma unroll
    for (int r = 0; r < 4; r++) {
      int lr = ty * 4 + r;
      float p = 0.0f;
#pragma unroll
      for (int c = 0; c < 4; c++) {
        float x = acc4[r][c] + b1v[c];
        p += sspf(x) * w2v[c];
        Ss[lr][n0 + c] = sigmf(x) * w2v[c];
      }
      red[lr][tx] = p;
    }
  }
  __syncthreads();
  if (t < 64) {
    int gm = m0 + t;
    if (gm < N_ATOMS) {
      float s = hb2[0];
#pragma unroll
      for (int j = 0; j < 16; j++) s += red[t][j];
      ea[gm] = s;
    }
  }

  float acc[4][8];
#pragma unroll
  for (int r = 0; r < 4; r++)
#pragma unroll
    for (int c = 0; c < 8; c++) acc[r][c] = 0.0f;

  for (int j0 = 0; j0 < 64; j0 += 16) {
#pragma unroll
    for (int it = 0; it < 2; it++) {
      int idx = t + it * 256;
      int n = idx >> 2;
      int jg = (idx & 3) * 4;
      float4 bv = *(const float4*)(hw1 + (size_t)n * 64 + j0 + jg);
      Bs[jg+0][n] = bv.x; Bs[jg+1][n] = bv.y;
      Bs[jg+2][n] = bv.z; Bs[jg+3][n] = bv.w;
    }
    __syncthreads();
#pragma unroll
    for (int kk = 0; kk < 16; kk++) {
      float a[4], b[8];
#pragma unroll
      for (int r = 0; r < 4; r++) a[r] = Ss[ty * 4 + r][j0 + kk];
#pragma unroll
      for (int c = 0; c < 8; c++) b[c] = Bs[kk][tx * 8 + c];
#pragma unroll
      for (int r = 0; r < 4; r++)
#pragma unroll
        for (int c = 0; c < 8; c++) acc[r][c] = fmaf(a[r], b[c], acc[r][c]);
    }
    __syncthreads();
  }

  int n0 = tx * 8;
#pragma unroll
  for (int r = 0; r < 4; r++) {
    int gm = m0 + ty * 4 + r;
    if (gm >= N_ATOMS) continue;
    *(float4*)(gh + (size_t)gm * HD + n0)     = *(float4*)&acc[r][0];
    *(float4*)(gh + (size_t)gm * HD + n0 + 4) = *(float4*)&acc[r][4];
  }
}

// ------------------------------------------------------------------
// per-molecule energy reduction
// ------------------------------------------------------------------
__global__ __launch_bounds__(64) void ered_k(
    const int* __restrict__ batch, const float* __restrict__ ea,
    float* __restrict__ energy)
{
  int m = blockIdx.x;
  int lo = 0, hi = N_ATOMS;
  while (lo < hi) { int mid = (lo + hi) >> 1; if (batch[mid] < m) lo = mid + 1; else hi = mid; }
  int beg = lo;
  lo = beg; hi = N_ATOMS;
  while (lo < hi) { int mid = (lo + hi) >> 1; if (batch[mid] < m + 1) lo = mid + 1; else hi = mid; }
  int end = lo;
  float s = 0.0f;
  for (int i = beg + threadIdx.x; i < end; i += 64) s += ea[i];
#pragma unroll
  for (int off = 32; off > 0; off >>= 1) s += __shfl_down(s, off, 64);
  if (threadIdx.x == 0) energy[m] = s;
}

// ------------------------------------------------------------------
// force gather
// ------------------------------------------------------------------
__global__ __launch_bounds__(256) void forceg_k(
    const int* __restrict__ rptr, const int* __restrict__ rother,
    const float* __restrict__ rdist,
    const int* __restrict__ cptr, const int* __restrict__ cother,
    const float* __restrict__ cdist, const int* __restrict__ cslot,
    const float* __restrict__ ddslot, const float* __restrict__ pos,
    float* __restrict__ force)
{
  int idx = blockIdx.x * 256 + threadIdx.x;
  int a = idx >> 3;
  int g = idx & 7;
  if (a >= N_ATOMS) return;
  float px = pos[3*a+0], py = pos[3*a+1], pz = pos[3*a+2];
  float fx = 0.f, fy = 0.f, fz = 0.f;
  int beg = rptr[a], end = rptr[a+1];
  for (int j = beg + g; j < end; j += 8) {
    int o = rother[j];
    float w = ddslot[j] / rdist[j];
    fx -= w * (px - pos[3*o+0]);
    fy -= w * (py - pos[3*o+1]);
    fz -= w * (pz - pos[3*o+2]);
  }
  beg = cptr[a]; end = cptr[a+1];
  for (int j = beg + g; j < end; j += 8) {
    int o = cother[j];
    float w = ddslot[cslot[j]] / cdist[j];
    fx -= w * (px - pos[3*o+0]);
    fy -= w * (py - pos[3*o+1]);
    fz -= w * (pz - pos[3*o+2]);
  }
#pragma unroll
  for (int off = 4; off > 0; off >>= 1) {
    fx += __shfl_down(fx, off, 8);
    fy += __shfl_down(fy, off, 8);
    fz += __shfl_down(fz, off, 8);
  }
  if (g == 0) {
    force[3*a+0] = fx;
    force[3*a+1] = fy;
    force[3*a+2] = fz;
  }
}

// ------------------------------------------------------------------
// host launch
// ------------------------------------------------------------------
static inline int nblk(int m) { return (m + 63) / 64; }

extern "C" void kernel_launch(void* const* d_in, const int* in_sizes, int n_in,
                              void* d_out, int out_size, void* d_ws, size_t ws_size,
                              hipStream_t stream)
{
  const float* pos   = (const float*)d_in[0];
  const int*   z     = (const int*)d_in[1];
  const int*   batch = (const int*)d_in[2];
  const int*   eidx  = (const int*)d_in[3];
  const float* emb   = (const float*)d_in[4];
  const float* mlp_w1 = (const float*)d_in[5];
  const float* mlp_b1 = (const float*)d_in[6];
  const float* mlp_w2 = (const float*)d_in[7];
  const float* mlp_b2 = (const float*)d_in[8];
  const float* lin1_w = (const float*)d_in[9];
  const float* lin2_w = (const float*)d_in[10];
  const float* lin2_b = (const float*)d_in[11];
  const float* blk_w  = (const float*)d_in[12];
  const float* blk_b  = (const float*)d_in[13];
  const float* hw1 = (const float*)d_in[14];
  const float* hb1 = (const float*)d_in[15];
  const float* hw2 = (const float*)d_in[16];
  const float* hb2 = (const float*)d_in[17];

  float* out = (float*)d_out;          // [NMOL] energies ++ [N,3] forces
  float* ws  = (float*)d_ws;

  const int* row = eidx;
  const int* col = eidx + N_EDGES;

  const size_t NH = (size_t)N_ATOMS * HD;
  size_t o = 0;
  float* dist   = ws + o; o += N_EDGES;
  float* ddslot = ws + o; o += N_EDGES;
  int* cptr   = (int*)(ws + o); o += N_ATOMS + 1;
  int* rptr   = (int*)(ws + o); o += N_ATOMS + 1;
  int* cother = (int*)(ws + o); o += N_EDGES;
  int* rother = (int*)(ws + o); o += N_EDGES;
  int* slotof = (int*)(ws + o); o += N_EDGES;
  int* cslot  = (int*)(ws + o); o += N_EDGES;
  float* cdist = ws + o; o += N_EDGES;
  float* rdist = ws + o; o += N_EDGES;
  int* cur0   = (int*)(ws + o); o += N_ATOMS;
  int* cur1   = (int*)(ws + o); o += N_ATOMS;
  // bf16 weights: wt = transposed (fwd), wp = plain (bwd); 16B-aligned
  o = (o + 3) & ~(size_t)3;
  u16* wt = (u16*)(ws + o); o += (size_t)NLAY * 3 * HD * HD / 2;
  u16* wp = (u16*)(ws + o); o += (size_t)NLAY * 3 * HD * HD / 2;
  float* hxb[4];   // stored as bf16 (128 u16 per row)
  for (int i = 0; i < 4; i++) { hxb[i] = ws + o; o += NH; }
  float* vbuf[4];
  for (int i = 0; i < 4; i++) { vbuf[i] = ws + o; o += NH; }
  float* hA  = ws + o; o += NH;
  float* hB  = ws + o; o += NH;
  float* agg = ws + o; o += NH;       // fwd agg / bwd dhx / table temps
  float* g0b = ws + o; o += NH;
  float* g1b = ws + o; o += NH;
  float* dgb = ws + o; o += NH;       // dagg(bf16) / ea / table temps

  // table: bf16 pairs, 1 uint per (node,ch)
  int NT = 1024;
  while (NT > 128) {
    size_t need = o + (size_t)NLAY * (NT + 1) * HD;
    if (need * sizeof(float) <= ws_size) break;
    NT >>= 1;
  }
  const int NN = NT + 1;
  const float hstep = FCUT / (float)NT;
  const float inv_h = (float)NT / FCUT;
  unsigned* T = (unsigned*)(ws + o); o += (size_t)NLAY * NN * HD;

  hipMemsetAsync(ddslot, 0, N_EDGES * sizeof(float), stream);

  geom_k<<<(N_EDGES + 255) / 256, 256, 0, stream>>>(pos, row, col, dist);
  wprep_k<<<(NLAY * 3 * HD * HD + 255) / 256, 256, 0, stream>>>(lin1_w, lin2_w, blk_w, wt, wp);

  // ---------------- CSR build (both directions) ----------------
  {
    const int EB = (N_EDGES + 255) / 256;
    hipMemsetAsync(cur0, 0, N_ATOMS * sizeof(int), stream);
    hipMemsetAsync(cur1, 0, N_ATOMS * sizeof(int), stream);
    hist_k<<<EB, 256, 0, stream>>>(col, cur0);
    hist_k<<<EB, 256, 0, stream>>>(row, cur1);
    scan_k<<<1, 256, 0, stream>>>(cur0, cptr);
    scan_k<<<1, 256, 0, stream>>>(cur1, rptr);
    hipMemcpyAsync(cur0, cptr, N_ATOMS * sizeof(int), hipMemcpyDeviceToDevice, stream);
    hipMemcpyAsync(cur1, rptr, N_ATOMS * sizeof(int), hipMemcpyDeviceToDevice, stream);
    scat_row_k<<<EB, 256, 0, stream>>>(row, col, dist, cur1, rother, rdist, slotof);
    scat_col_k<<<EB, 256, 0, stream>>>(row, col, dist, cur0, cother, cdist, slotof, cslot);
  }

  // ---------------- build filter tables (all 4 layers) ----------------
  {
    const size_t LNH = (size_t)NN * HD;
    float* Anode  = agg;
    float* dAnode = agg + LNH;
    float* t1 = dgb;
    float* u  = g0b;
    float* s  = g1b;
    float* sp = hA;
    nodeA_k<<<((int)LNH + 255) / 256, 256, 0, stream>>>(Anode, dAnode, NN, hstep);
    dim3 gB(nblk(NN), NLAY);
    gemm128b_k<<<gB, 256, 0, stream>>>(Anode, 0, mlp_w1, (size_t)HD*HD,
                                       mlp_b1, HD, t1, LNH, NN);
    gemm128b_k<<<gB, 256, 0, stream>>>(dAnode, 0, mlp_w1, (size_t)HD*HD,
                                       nullptr, 0, u, LNH, NN);
    int tot = (int)(NLAY * LNH);
    nodeact_k<<<(tot + 255) / 256, 256, 0, stream>>>(t1, u, s, sp, tot);
    float* P0 = dgb;
    float* D0 = g0b;
    gemm128b_k<<<gB, 256, 0, stream>>>(s, LNH, mlp_w2, (size_t)HD*HD,
                                       mlp_b2, HD, P0, LNH, NN);
    gemm128b_k<<<gB, 256, 0, stream>>>(sp, LNH, mlp_w2, (size_t)HD*HD,
                                       nullptr, 0, D0, LNH, NN);
    nodecomb_k<<<(tot + 255) / 256, 256, 0, stream>>>(P0, D0, T, NN, hstep);
  }

  h0_k<<<(N_ATOMS * HD + 255) / 256, 256, 0, stream>>>(emb, z, hA);

  const int AB = (N_ATOMS + 3) / 4;
  const int GB = nblk(N_ATOMS);

  // ---------------- forward ----------------
  float* hcur = hA;
  float* hnxt = hB;
  for (int i = 0; i < NLAY; i++) {
    const u16* l1t = wt + ((size_t)(i*3 + 0) << 14);
    const u16* l2t = wt + ((size_t)(i*3 + 1) << 14);
    const u16* bwt = wt + ((size_t)(i*3 + 2) << 14);
    const float* l2bi = lin2_b + (size_t)i * HD;
    const float* bbi  = blk_b + (size_t)i * HD;
    const unsigned* Tl = T + (size_t)i * NN * HD;

    mm_hx_k<<<GB, 256, 0, stream>>>(hcur, l1t, (u16*)hxb[i], N_ATOMS);
    gath_fwd_k<<<AB, 256, 0, stream>>>(cptr, cother, cdist, Tl, (const unsigned*)hxb[i], agg, inv_h, hstep);
    ftail_mfma_k<<<GB, 256, 0, stream>>>(agg, l2t, l2bi, bwt, bbi, hcur, vbuf[i], hnxt, N_ATOMS);
    float* tmp = hcur; hcur = hnxt; hnxt = tmp;
  }

  // ---------------- head (fused) + per-molecule energy ----------------
  float* ea = dgb;   // per-atom energy scratch; dgb free here
  headf_k<<<GB, 256, 0, stream>>>(hcur, hw1, hb1, hw2, hb2, ea, g0b);
  ered_k<<<NMOL, 64, 0, stream>>>(batch, ea, out);

  // ---------------- backward ----------------
  float* gcur = g0b;
  float* gnxt = g1b;
  for (int i = NLAY - 1; i >= 0; i--) {
    const u16* l1p = wp + ((size_t)(i*3 + 0) << 14);
    const u16* l2p = wp + ((size_t)(i*3 + 1) << 14);
    const u16* bwp = wp + ((size_t)(i*3 + 2) << 14);
    const unsigned* Tl = T + (size_t)i * NN * HD;

    bhead_mfma_k<<<GB, 256, 0, stream>>>(gcur, bwp, vbuf[i], l2p, (u16*)dgb, N_ATOMS);
    gath_bwd_k<<<AB, 256, 0, stream>>>(rptr, rother, rdist, Tl, (const unsigned*)dgb,
                                       (const unsigned*)hxb[i], agg, ddslot, inv_h, hstep);
    if (i > 0) {
      mm_bwdT_k<<<GB, 256, 0, stream>>>(agg, l1p, gcur, gnxt, N_ATOMS);
      float* tmp = gcur; gcur = gnxt; gnxt = tmp;
    }
  }

  forceg_k<<<(N_ATOMS * 8 + 255) / 256, 256, 0, stream>>>(
      rptr, rother, rdist, cptr, cother, cdist, cslot, ddslot, pos, out + NMOL);
}

// Round 3
// 986.329 us; speedup vs baseline: 1.1866x; 1.0214x over previous
//
#include <hip/hip_runtime.h>

#define HD 128

constexpr int N_ATOMS = 20000;
constexpr int N_EDGES = 320000;
constexpr int NLAY   = 4;
constexpr int NMOL   = 200;
constexpr float FCUT  = 5.0f;
constexpr float DELTA = FCUT / 127.0f;
constexpr float GCOEFF = -0.5f / (DELTA * DELTA);
constexpr float PI_F  = 3.14159265358979323846f;
constexpr float LN2F  = 0.6931471805599453f;

typedef unsigned short u16;
typedef __attribute__((ext_vector_type(8))) short short8v;
typedef __attribute__((ext_vector_type(4))) float f32x4;

__device__ __forceinline__ float sspf(float x) {
  return fmaxf(x, 0.0f) + log1pf(expf(-fabsf(x))) - LN2F;
}
__device__ __forceinline__ float sigmf(float x) {
  return 1.0f / (1.0f + expf(-x));
}

// bf16 pack/unpack (round-to-nearest-even)
__device__ __forceinline__ unsigned bfpack(float a, float b) {
  unsigned ua = __float_as_uint(a);
  unsigned ub = __float_as_uint(b);
  ua = (ua + 0x7FFFu + ((ua >> 16) & 1u)) >> 16;
  ub = (ub + 0x7FFFu + ((ub >> 16) & 1u)) >> 16;
  return (ub << 16) | ua;
}
__device__ __forceinline__ float bflo(unsigned p) { return __uint_as_float(p << 16); }
__device__ __forceinline__ float bfhi(unsigned p) { return __uint_as_float(p & 0xFFFF0000u); }
__device__ __forceinline__ u16 f2bf(float x) {
  unsigned u = __float_as_uint(x);
  u = (u + 0x7FFFu + ((u >> 16) & 1u)) >> 16;
  return (u16)u;
}

// split f (f32) into hi bf16 (truncate) + lo bf16 (truncate of remainder),
// packed as u32: upper16 = hi bits, lower16 = lo bits
__device__ __forceinline__ unsigned packhl(float s) {
  unsigned hs = __float_as_uint(s) & 0xffff0000u;
  float lo = s - __uint_as_float(hs);
  return hs | (__float_as_uint(lo) >> 16);
}

// two f32 (bit patterns a,b) -> hi-pair uint (shorts [hi(a),hi(b)]) and lo-pair
__device__ __forceinline__ unsigned hpair_f32(unsigned a, unsigned b, unsigned& lopair) {
  unsigned ha = a & 0xffff0000u, hb = b & 0xffff0000u;
  float la = __uint_as_float(a) - __uint_as_float(ha);
  float lb = __uint_as_float(b) - __uint_as_float(hb);
  lopair = (__float_as_uint(lb) & 0xffff0000u) | (__float_as_uint(la) >> 16);
  return hb | (ha >> 16);
}

// ------------------------------------------------------------------
// small elementwise kernels
// ------------------------------------------------------------------

__global__ __launch_bounds__(256) void geom_k(
    const float* __restrict__ pos, const int* __restrict__ row,
    const int* __restrict__ col, float* __restrict__ dist)
{
  int e = blockIdx.x * 256 + threadIdx.x;
  if (e >= N_EDGES) return;
  int r = row[e], c = col[e];
  float dx = pos[3*r+0] - pos[3*c+0];
  float dy = pos[3*r+1] - pos[3*c+1];
  float dz = pos[3*r+2] - pos[3*c+2];
  dist[e] = sqrtf(dx*dx + dy*dy + dz*dz);
}

__global__ __launch_bounds__(256) void h0_k(
    const float* __restrict__ emb, const int* __restrict__ z,
    float* __restrict__ h0)
{
  int i = blockIdx.x * 256 + threadIdx.x;
  if (i >= N_ATOMS * HD) return;
  int n = i >> 7, k = i & 127;
  h0[i] = emb[z[n] * HD + k];
}

// bf16 weight prep:
//  wsel 0..2 (lin1,lin2,blk): wp = bf16(W) row-major, wt = bf16(W^T)
//  wsel 3..4 (mlp_w1,mlp_w2): mt = bf16(W^T) only
__global__ __launch_bounds__(256) void wprep_k(
    const float* __restrict__ l1, const float* __restrict__ l2,
    const float* __restrict__ bw, const float* __restrict__ mw1,
    const float* __restrict__ mw2,
    u16* __restrict__ wt, u16* __restrict__ wp, u16* __restrict__ mt)
{
  int i = blockIdx.x * 256 + threadIdx.x;
  if (i >= NLAY * 5 * HD * HD) return;
  int e = i & (HD * HD - 1);
  int wl = i >> 14;
  int wsel = wl % 5;
  int lay = wl / 5;
  const float* W;
  if      (wsel == 0) W = l1;
  else if (wsel == 1) W = l2;
  else if (wsel == 2) W = bw;
  else if (wsel == 3) W = mw1;
  else                W = mw2;
  W += (size_t)lay * HD * HD;
  u16 b = f2bf(W[e]);
  int k = e >> 7, n = e & 127;
  if (wsel < 3) {
    size_t base = (size_t)(lay * 3 + wsel) << 14;
    wp[base + e] = b;
    wt[base + (size_t)n * HD + k] = b;
  } else {
    size_t base = (size_t)(lay * 2 + (wsel - 3)) << 14;
    mt[base + (size_t)n * HD + k] = b;
  }
}

// ------------------------------------------------------------------
// CSR build: histogram, scan, scatter
// ------------------------------------------------------------------
__global__ __launch_bounds__(256) void hist_k(
    const int* __restrict__ idx, int* __restrict__ cnt)
{
  int e = blockIdx.x * 256 + threadIdx.x;
  if (e >= N_EDGES) return;
  atomicAdd(&cnt[idx[e]], 1);
}

__global__ __launch_bounds__(256) void scan_k(
    const int* __restrict__ cnt, int* __restrict__ ptr)
{
  constexpr int CH = 79;  // 256*79 = 20224 >= 20001
  __shared__ int part[256];
  int t = threadIdx.x;
  int base = t * CH;
  int s = 0;
  for (int i = 0; i < CH; i++) {
    int idx = base + i;
    if (idx < N_ATOMS) s += cnt[idx];
  }
  part[t] = s;
  __syncthreads();
  for (int off = 1; off < 256; off <<= 1) {
    int u = (t >= off) ? part[t - off] : 0;
    __syncthreads();
    part[t] += u;
    __syncthreads();
  }
  int run = part[t] - s;
  for (int i = 0; i < CH; i++) {
    int idx = base + i;
    if (idx > N_ATOMS) break;
    ptr[idx] = run;
    if (idx < N_ATOMS) run += cnt[idx];
  }
}

__global__ __launch_bounds__(256) void scat_row_k(
    const int* __restrict__ row, const int* __restrict__ col,
    const float* __restrict__ dist, int* __restrict__ cur,
    int* __restrict__ rother, float* __restrict__ rdist,
    int* __restrict__ slotof)
{
  int e = blockIdx.x * 256 + threadIdx.x;
  if (e >= N_EDGES) return;
  int p = atomicAdd(&cur[row[e]], 1);
  rother[p] = col[e];
  rdist[p] = dist[e];
  slotof[e] = p;
}

__global__ __launch_bounds__(256) void scat_col_k(
    const int* __restrict__ row, const int* __restrict__ col,
    const float* __restrict__ dist, int* __restrict__ cur,
    int* __restrict__ cother, float* __restrict__ cdist,
    const int* __restrict__ slotof, int* __restrict__ cslot)
{
  int e = blockIdx.x * 256 + threadIdx.x;
  if (e >= N_EDGES) return;
  int p = atomicAdd(&cur[col[e]], 1);
  cother[p] = row[e];
  cdist[p] = dist[e];
  cslot[p] = slotof[e];
}

// ------------------------------------------------------------------
// table build
// ------------------------------------------------------------------
__global__ __launch_bounds__(256) void nodeA_k(
    float* __restrict__ A, float* __restrict__ dA, int nnode, float hstep)
{
  int i = blockIdx.x * 256 + threadIdx.x;
  if (i >= nnode * HD) return;
  int node = i >> 7, g = i & 127;
  float d = (float)node * hstep;
  float t = d - (float)g * DELTA;
  float a = expf(GCOEFF * t * t);
  A[i] = a;
  dA[i] = a * 2.0f * GCOEFF * t;
}

__global__ __launch_bounds__(256) void nodeact_k(
    const float* __restrict__ t1, const float* __restrict__ u,
    float* __restrict__ s, float* __restrict__ sp, int total)
{
  int i = blockIdx.x * 256 + threadIdx.x;
  if (i >= total) return;
  float x = t1[i];
  s[i] = sspf(x);
  sp[i] = sigmf(x) * u[i];
}

__global__ __launch_bounds__(256) void nodecomb_k(
    const float* __restrict__ P0, const float* __restrict__ D0,
    unsigned* __restrict__ T, int nnode, float hstep)
{
  int i = blockIdx.x * 256 + threadIdx.x;
  int total = NLAY * nnode * HD;
  if (i >= total) return;
  int rem = i % (nnode * HD);
  int node = rem >> 7;
  float d = (float)node * hstep;
  float C  = 0.5f * cosf(d * (PI_F / FCUT)) + 0.5f;
  float Cp = -0.5f * sinf(d * (PI_F / FCUT)) * (PI_F / FCUT);
  float p = P0[i], q = D0[i];
  T[i] = bfpack(p * C, q * C + p * Cp);
}

// ------------------------------------------------------------------
// no-LDS MFMA wave GEMM: wave computes rows [m0,m0+16) x cols
// [wbase,wbase+32) of C = A[M,128] @ B[128,128].
// Bt buffer layout: Bt[n*HD + k] = B[k][n] (bf16).
// A fragment loaded per-lane directly from global (lane -> row lane&15,
// k-octet (lane>>4)*8), split hi/lo bf16 in registers.
// AIN: 0 = f32 input, 1 = packed u32 (hi16|lo16) input.
// No LDS, no barriers: waves fully independent -> high occupancy.
// ------------------------------------------------------------------
template<int AIN>
__device__ __forceinline__ void wave_mm(
    const void* __restrict__ Av, const u16* __restrict__ Bt,
    int m0, int wbase, int lc, int lg, int mclamp, f32x4 acc[2])
{
  short8v bfr[4][2];
#pragma unroll
  for (int ks = 0; ks < 4; ++ks)
#pragma unroll
    for (int nt = 0; nt < 2; ++nt)
      bfr[ks][nt] = *(const short8v*)(Bt + (size_t)(wbase + nt*16 + lc) * HD + ks*32 + lg*8);
  int ar = m0 + lc;
  if (ar > mclamp) ar = mclamp;   // row-clamped load; garbage rows never stored
  f32x4 z = {0.f, 0.f, 0.f, 0.f};
  acc[0] = z; acc[1] = z;
#pragma unroll
  for (int ks = 0; ks < 4; ++ks) {
    short8v ah, al;
    if (AIN == 0) {
      const float* p = (const float*)Av + (size_t)ar * HD + ks*32 + lg*8;
      uint4 u0 = *(const uint4*)p;
      uint4 u1 = *(const uint4*)(p + 4);
      unsigned p0l, p1l, p2l, p3l;
      unsigned p0h = hpair_f32(u0.x, u0.y, p0l);
      unsigned p1h = hpair_f32(u0.z, u0.w, p1l);
      unsigned p2h = hpair_f32(u1.x, u1.y, p2l);
      unsigned p3h = hpair_f32(u1.z, u1.w, p3l);
      uint4 hv = make_uint4(p0h, p1h, p2h, p3h);
      uint4 lv = make_uint4(p0l, p1l, p2l, p3l);
      ah = *(short8v*)&hv; al = *(short8v*)&lv;
    } else {
      const unsigned* p = (const unsigned*)Av + (size_t)ar * HD + ks*32 + lg*8;
      uint4 u0 = *(const uint4*)p;
      uint4 u1 = *(const uint4*)(p + 4);
      uint4 hv = make_uint4(
        (u0.y & 0xffff0000u) | (u0.x >> 16),
        (u0.w & 0xffff0000u) | (u0.z >> 16),
        (u1.y & 0xffff0000u) | (u1.x >> 16),
        (u1.w & 0xffff0000u) | (u1.z >> 16));
      uint4 lv = make_uint4(
        (u0.y << 16) | (u0.x & 0xffffu),
        (u0.w << 16) | (u0.z & 0xffffu),
        (u1.y << 16) | (u1.x & 0xffffu),
        (u1.w << 16) | (u1.z & 0xffffu));
      ah = *(short8v*)&hv; al = *(short8v*)&lv;
    }
    acc[0] = __builtin_amdgcn_mfma_f32_16x16x32_bf16(ah, bfr[ks][0], acc[0], 0, 0, 0);
    acc[1] = __builtin_amdgcn_mfma_f32_16x16x32_bf16(ah, bfr[ks][1], acc[1], 0, 0, 0);
    acc[0] = __builtin_amdgcn_mfma_f32_16x16x32_bf16(al, bfr[ks][0], acc[0], 0, 0, 0);
    acc[1] = __builtin_amdgcn_mfma_f32_16x16x32_bf16(al, bfr[ks][1], acc[1], 0, 0, 0);
  }
}

// hx = h @ W  (Bt = W^T bf16), output u16 bf16
__global__ __launch_bounds__(256) void nmm_hx_k(
    const float* __restrict__ h, const u16* __restrict__ Bt,
    u16* __restrict__ hx, int M)
{
  int t = threadIdx.x, lane = t & 63;
  int lc = lane & 15, lg = lane >> 4;
  int wbase = (t >> 6) * 32;
  int m0 = blockIdx.x * 16;
  f32x4 acc[2];
  wave_mm<0>(h, Bt, m0, wbase, lc, lg, M - 1, acc);
#pragma unroll
  for (int nt = 0; nt < 2; ++nt) {
    int ccol = wbase + nt*16 + lc;
#pragma unroll
    for (int j = 0; j < 4; ++j) {
      int grow = m0 + lg*4 + j;
      if (grow < M) hx[(size_t)grow * HD + ccol] = f2bf(acc[nt][j]);
    }
  }
}

// C = A @ W^T + addin  (Bp = W bf16 row-major), fp32 out
__global__ __launch_bounds__(256) void nmm_bwdT_k(
    const float* __restrict__ A, const u16* __restrict__ Bp,
    const float* __restrict__ addin, float* __restrict__ C, int M)
{
  int t = threadIdx.x, lane = t & 63;
  int lc = lane & 15, lg = lane >> 4;
  int wbase = (t >> 6) * 32;
  int m0 = blockIdx.x * 16;
  f32x4 acc[2];
  wave_mm<0>(A, Bp, m0, wbase, lc, lg, M - 1, acc);
#pragma unroll
  for (int nt = 0; nt < 2; ++nt) {
    int ccol = wbase + nt*16 + lc;
#pragma unroll
    for (int j = 0; j < 4; ++j) {
      int grow = m0 + lg*4 + j;
      if (grow < M)
        C[(size_t)grow * HD + ccol] = acc[nt][j] + addin[(size_t)grow * HD + ccol];
    }
  }
}

// fwd tail 1: V = agg@l2 + l2b (store f32) ; spk = packhl(ssp(V))
__global__ __launch_bounds__(256) void ftail1_k(
    const float* __restrict__ agg, const u16* __restrict__ l2t,
    const float* __restrict__ l2b, float* __restrict__ vbuf,
    unsigned* __restrict__ spk, int M)
{
  int t = threadIdx.x, lane = t & 63;
  int lc = lane & 15, lg = lane >> 4;
  int wbase = (t >> 6) * 32;
  int m0 = blockIdx.x * 16;
  f32x4 acc[2];
  wave_mm<0>(agg, l2t, m0, wbase, lc, lg, M - 1, acc);
#pragma unroll
  for (int nt = 0; nt < 2; ++nt) {
    int ccol = wbase + nt*16 + lc;
    float bv = l2b[ccol];
#pragma unroll
    for (int j = 0; j < 4; ++j) {
      int grow = m0 + lg*4 + j;
      if (grow < M) {
        float x = acc[nt][j] + bv;
        vbuf[(size_t)grow * HD + ccol] = x;
        spk[(size_t)grow * HD + ccol] = packhl(sspf(x));
      }
    }
  }
}

// fwd tail 2: hout = spk @ bw + bb + h
__global__ __launch_bounds__(256) void ftail2_k(
    const unsigned* __restrict__ spk, const u16* __restrict__ bwt,
    const float* __restrict__ bb, const float* __restrict__ h,
    float* __restrict__ hout, int M)
{
  int t = threadIdx.x, lane = t & 63;
  int lc = lane & 15, lg = lane >> 4;
  int wbase = (t >> 6) * 32;
  int m0 = blockIdx.x * 16;
  f32x4 acc[2];
  wave_mm<1>(spk, bwt, m0, wbase, lc, lg, M - 1, acc);
#pragma unroll
  for (int nt = 0; nt < 2; ++nt) {
    int ccol = wbase + nt*16 + lc;
    float bv = bb[ccol];
#pragma unroll
    for (int j = 0; j < 4; ++j) {
      int grow = m0 + lg*4 + j;
      if (grow < M)
        hout[(size_t)grow * HD + ccol] =
            acc[nt][j] + bv + h[(size_t)grow * HD + ccol];
    }
  }
}

// bwd head 1: dv = (g@bw^T)*sigm(v) -> packed hi/lo
__global__ __launch_bounds__(256) void bhead1_k(
    const float* __restrict__ g, const u16* __restrict__ bwp,
    const float* __restrict__ v, unsigned* __restrict__ dvpk, int M)
{
  int t = threadIdx.x, lane = t & 63;
  int lc = lane & 15, lg = lane >> 4;
  int wbase = (t >> 6) * 32;
  int m0 = blockIdx.x * 16;
  f32x4 acc[2];
  wave_mm<0>(g, bwp, m0, wbase, lc, lg, M - 1, acc);
#pragma unroll
  for (int nt = 0; nt < 2; ++nt) {
    int ccol = wbase + nt*16 + lc;
#pragma unroll
    for (int j = 0; j < 4; ++j) {
      int grow = m0 + lg*4 + j;
      if (grow < M) {
        float dv = acc[nt][j] * sigmf(v[(size_t)grow * HD + ccol]);
        dvpk[(size_t)grow * HD + ccol] = packhl(dv);
      }
    }
  }
}

// bwd head 2: dagg = dv @ l2^T (bf16 u16 out)
__global__ __launch_bounds__(256) void bhead2_k(
    const unsigned* __restrict__ dvpk, const u16* __restrict__ l2p,
    u16* __restrict__ dagg, int M)
{
  int t = threadIdx.x, lane = t & 63;
  int lc = lane & 15, lg = lane >> 4;
  int wbase = (t >> 6) * 32;
  int m0 = blockIdx.x * 16;
  f32x4 acc[2];
  wave_mm<1>(dvpk, l2p, m0, wbase, lc, lg, M - 1, acc);
#pragma unroll
  for (int nt = 0; nt < 2; ++nt) {
    int ccol = wbase + nt*16 + lc;
#pragma unroll
    for (int j = 0; j < 4; ++j) {
      int grow = m0 + lg*4 + j;
      if (grow < M) dagg[(size_t)grow * HD + ccol] = f2bf(acc[nt][j]);
    }
  }
}

// batched (blockIdx.y = layer) table-build GEMM, f32 in/out, bias opt
__global__ __launch_bounds__(256) void tblmm_k(
    const float* __restrict__ A, size_t astride,
    const u16* __restrict__ Bt, size_t bstride,
    const float* __restrict__ bias, size_t biasstride,
    float* __restrict__ C, size_t cstride, int M)
{
  int l = blockIdx.y;
  A += (size_t)l * astride;
  Bt += (size_t)l * bstride;
  if (bias) bias += (size_t)l * biasstride;
  C += (size_t)l * cstride;
  int t = threadIdx.x, lane = t & 63;
  int lc = lane & 15, lg = lane >> 4;
  int wbase = (t >> 6) * 32;
  int m0 = blockIdx.x * 16;
  f32x4 acc[2];
  wave_mm<0>(A, Bt, m0, wbase, lc, lg, M - 1, acc);
#pragma unroll
  for (int nt = 0; nt < 2; ++nt) {
    int ccol = wbase + nt*16 + lc;
    float bv = bias ? bias[ccol] : 0.0f;
#pragma unroll
    for (int j = 0; j < 4; ++j) {
      int grow = m0 + lg*4 + j;
      if (grow < M) C[(size_t)grow * HD + ccol] = acc[nt][j] + bv;
    }
  }
}

// ------------------------------------------------------------------
// forward gather: agg[a] = sum_in hx[src] * P(d); bf16 table + hx
// ------------------------------------------------------------------
__global__ __launch_bounds__(256) void gath_fwd_k(
    const int* __restrict__ cptr, const int* __restrict__ cother,
    const float* __restrict__ cdist, const unsigned* __restrict__ T,
    const unsigned* __restrict__ hx, float* __restrict__ agg,
    float inv_h, float hstep)
{
  int a = blockIdx.x * 4 + (threadIdx.x >> 6);
  if (a >= N_ATOMS) return;
  int half = (threadIdx.x >> 5) & 1;
  int l32 = threadIdx.x & 31;
  int ch = l32 * 4;
  int beg = cptr[a], end = cptr[a + 1];
  float s0 = 0.f, s1 = 0.f, s2 = 0.f, s3 = 0.f;
#pragma unroll 2
  for (int j = beg + half; j < end; j += 2) {
    int other = cother[j];
    float d = cdist[j];
    float fi = d * inv_h;
    int i0 = (int)fi;
    float t = fi - (float)i0;
    float t2 = t * t, t3 = t2 * t;
    float a00 = 2.f*t3 - 3.f*t2 + 1.f;
    float a10 = (t3 - 2.f*t2 + t) * hstep;
    float a01 = 3.f*t2 - 2.f*t3;
    float a11 = (t3 - t2) * hstep;
    const unsigned* tp = T + (size_t)i0 * HD + ch;
    uint4 q0 = *(const uint4*)(tp);
    uint4 q1 = *(const uint4*)(tp + HD);
    uint2 hp = *(const uint2*)(hx + (size_t)other * 64 + l32 * 2);
    float v0 = a00*bflo(q0.x) + a10*bfhi(q0.x) + a01*bflo(q1.x) + a11*bfhi(q1.x);
    float v1 = a00*bflo(q0.y) + a10*bfhi(q0.y) + a01*bflo(q1.y) + a11*bfhi(q1.y);
    float v2 = a00*bflo(q0.z) + a10*bfhi(q0.z) + a01*bflo(q1.z) + a11*bfhi(q1.z);
    float v3 = a00*bflo(q0.w) + a10*bfhi(q0.w) + a01*bflo(q1.w) + a11*bfhi(q1.w);
    s0 = fmaf(bflo(hp.x), v0, s0);
    s1 = fmaf(bfhi(hp.x), v1, s1);
    s2 = fmaf(bflo(hp.y), v2, s2);
    s3 = fmaf(bfhi(hp.y), v3, s3);
  }
  s0 += __shfl_xor(s0, 32, 64);
  s1 += __shfl_xor(s1, 32, 64);
  s2 += __shfl_xor(s2, 32, 64);
  s3 += __shfl_xor(s3, 32, 64);
  if (half == 0)
    *(float4*)(agg + (size_t)a * HD + ch) = make_float4(s0, s1, s2, s3);
}

// ------------------------------------------------------------------
// backward gather
// ------------------------------------------------------------------
__global__ __launch_bounds__(256) void gath_bwd_k(
    const int* __restrict__ rptr, const int* __restrict__ rother,
    const float* __restrict__ rdist, const unsigned* __restrict__ T,
    const unsigned* __restrict__ dagg, const unsigned* __restrict__ hx,
    float* __restrict__ dhx, float* __restrict__ ddslot,
    float inv_h, float hstep)
{
  int a = blockIdx.x * 4 + (threadIdx.x >> 6);
  if (a >= N_ATOMS) return;
  int half = (threadIdx.x >> 5) & 1;
  int l32 = threadIdx.x & 31;
  int ch = l32 * 4;
  int beg = rptr[a], end = rptr[a + 1];
  uint2 hp = *(const uint2*)(hx + (size_t)a * 64 + l32 * 2);
  float h0 = bflo(hp.x), h1 = bfhi(hp.x), h2 = bflo(hp.y), h3 = bfhi(hp.y);
  float s0 = 0.f, s1 = 0.f, s2 = 0.f, s3 = 0.f;
#pragma unroll 2
  for (int j = beg + half; j < end; j += 2) {
    int other = rother[j];
    float d = rdist[j];
    float fi = d * inv_h;
    int i0 = (int)fi;
    float t = fi - (float)i0;
    float t2 = t * t, t3 = t2 * t;
    float a00 = 2.f*t3 - 3.f*t2 + 1.f;
    float a10 = (t3 - 2.f*t2 + t) * hstep;
    float a01 = 3.f*t2 - 2.f*t3;
    float a11 = (t3 - t2) * hstep;
    float b00 = (6.f*t2 - 6.f*t) * inv_h;
    float b10 = 3.f*t2 - 4.f*t + 1.f;
    float b01 = -b00;
    float b11 = 3.f*t2 - 2.f*t;
    const unsigned* tp = T + (size_t)i0 * HD + ch;
    uint4 q0 = *(const uint4*)(tp);
    uint4 q1 = *(const uint4*)(tp + HD);
    uint2 dp = *(const uint2*)(dagg + (size_t)other * 64 + l32 * 2);
    float da0 = bflo(dp.x), da1 = bfhi(dp.x), da2 = bflo(dp.y), da3 = bfhi(dp.y);
    float v0 = a00*bflo(q0.x) + a10*bfhi(q0.x) + a01*bflo(q1.x) + a11*bfhi(q1.x);
    float v1 = a00*bflo(q0.y) + a10*bfhi(q0.y) + a01*bflo(q1.y) + a11*bfhi(q1.y);
    float v2 = a00*bflo(q0.z) + a10*bfhi(q0.z) + a01*bflo(q1.z) + a11*bfhi(q1.z);
    float v3 = a00*bflo(q0.w) + a10*bfhi(q0.w) + a01*bflo(q1.w) + a11*bfhi(q1.w);
    float g0 = b00*bflo(q0.x) + b10*bfhi(q0.x) + b01*bflo(q1.x) + b11*bfhi(q1.x);
    float g1 = b00*bflo(q0.y) + b10*bfhi(q0.y) + b01*bflo(q1.y) + b11*bfhi(q1.y);
    float g2 = b00*bflo(q0.z) + b10*bfhi(q0.z) + b01*bflo(q1.z) + b11*bfhi(q1.z);
    float g3 = b00*bflo(q0.w) + b10*bfhi(q0.w) + b01*bflo(q1.w) + b11*bfhi(q1.w);
    s0 = fmaf(da0, v0, s0);
    s1 = fmaf(da1, v1, s1);
    s2 = fmaf(da2, v2, s2);
    s3 = fmaf(da3, v3, s3);
    float dot = da0*h0*g0 + da1*h1*g1 + da2*h2*g2 + da3*h3*g3;
#pragma unroll
    for (int off = 16; off > 0; off >>= 1) dot += __shfl_down(dot, off, 32);
    if (l32 == 0) ddslot[j] += dot;
  }
  s0 += __shfl_xor(s0, 32, 64);
  s1 += __shfl_xor(s1, 32, 64);
  s2 += __shfl_xor(s2, 32, 64);
  s3 += __shfl_xor(s3, 32, 64);
  if (half == 0)
    *(float4*)(dhx + (size_t)a * HD + ch) = make_float4(s0, s1, s2, s3);
}

// ------------------------------------------------------------------
// fused head: s = h4@hw1 + hb1; ea[a] = ssp(s)@hw2 + hb2;
// gh = (sigm(s)*hw2) @ hw1^T
// ------------------------------------------------------------------
__global__ __launch_bounds__(256) void headf_k(
    const float* __restrict__ h4, const float* __restrict__ hw1,
    const float* __restrict__ hb1, const float* __restrict__ hw2,
    const float* __restrict__ hb2, float* __restrict__ ea,
    float* __restrict__ gh)
{
  __shared__ float As[16][68];
  __shared__ float Bs[16][132];
  __shared__ float Ss[64][68];
  __shared__ float red[64][17];
  int t = threadIdx.x;
  int tx = t & 15, ty = t >> 4;
  int m0 = blockIdx.x * 64;

  float acc4[4][4];
#pragma unroll
  for (int r = 0; r < 4; r++)
#pragma unroll
    for (int c = 0; c < 4; c++) acc4[r][c] = 0.0f;

  for (int k0 = 0; k0 < HD; k0 += 16) {
    {
      int rrow = t >> 2;
      int kg = (t & 3) * 4;
      int gm = m0 + rrow;
      float4 av = make_float4(0.f, 0.f, 0.f, 0.f);
      if (gm < N_ATOMS) av = *(const float4*)(h4 + (size_t)gm * HD + k0 + kg);
      As[kg+0][rrow] = av.x; As[kg+1][rrow] = av.y;
      As[kg+2][rrow] = av.z; As[kg+3][rrow] = av.w;
    }
    if (t < 256) {
      int kk = t >> 4;
      int n4 = (t & 15) * 4;
      float4 bv = *(const float4*)(hw1 + (size_t)(k0 + kk) * 64 + n4);
      *(float4*)&Bs[kk][n4] = bv;
    }
    __syncthreads();
#pragma unroll
    for (int kk = 0; kk < 16; kk++) {
      float a[4], b[4];
#pragma unroll
      for (int r = 0; r < 4; r++) a[r] = As[kk][ty * 4 + r];
#pragma unroll
      for (int c = 0; c < 4; c++) b[c] = Bs[kk][tx * 4 + c];
#pragma unroll
      for (int r = 0; r < 4; r++)
#pragma unroll
        for (int c = 0; c < 4; c++) acc4[r][c] = fmaf(a[r], b[c], acc4[r][c]);
    }
    __syncthreads();
  }

  {
    int n0 = tx * 4;
    float b1v[4], w2v[4];
#pragma unroll
    for (int c = 0; c < 4; c++) { b1v[c] = hb1[n0 + c]; w2v[c] = hw2[n0 + c]; }
#pragma unroll
    for (int r = 0; r < 4; r++) {
      int lr = ty * 4 + r;
      float p = 0.0f;
#pragma unroll
      for (int c = 0; c < 4; c++) {
        float x = acc4[r][c] + b1v[c];
        p += sspf(x) * w2v[c];
        Ss[lr][n0 + c] = sigmf(x) * w2v[c];
      }
      red[lr][tx] = p;
    }
  }
  __syncthreads();
  if (t < 64) {
    int gm = m0 + t;
    if (gm < N_ATOMS) {
      float s = hb2[0];
#pragma unroll
      for (int j = 0; j < 16; j++) s += red[t][j];
      ea[gm] = s;
    }
  }

  float acc[4][8];
#pragma unroll
  for (int r = 0; r < 4; r++)
#pragma unroll
    for (int c = 0; c < 8; c++) acc[r][c] = 0.0f;

  for (int j0 = 0; j0 < 64; j0 += 16) {
#pragma unroll
    for (int it = 0; it < 2; it++) {
      int idx = t + it * 256;
      int n = idx >> 2;
      int jg = (idx & 3) * 4;
      float4 bv = *(const float4*)(hw1 + (size_t)n * 64 + j0 + jg);
      Bs[jg+0][n] = bv.x; Bs[jg+1][n] = bv.y;
      Bs[jg+2][n] = bv.z; Bs[jg+3][n] = bv.w;
    }
    __syncthreads();
#pragma unroll
    for (int kk = 0; kk < 16; kk++) {
      float a[4], b[8];
#pragma unroll
      for (int r = 0; r < 4; r++) a[r] = Ss[ty * 4 + r][j0 + kk];
#pragma unroll
      for (int c = 0; c < 8; c++) b[c] = Bs[kk][tx * 8 + c];
#pragma unroll
      for (int r = 0; r < 4; r++)
#pragma unroll
        for (int c = 0; c < 8; c++) acc[r][c] = fmaf(a[r], b[c], acc[r][c]);
    }
    __syncthreads();
  }

  int n0 = tx * 8;
#pragma unroll
  for (int r = 0; r < 4; r++) {
    int gm = m0 + ty * 4 + r;
    if (gm >= N_ATOMS) continue;
    *(float4*)(gh + (size_t)gm * HD + n0)     = *(float4*)&acc[r][0];
    *(float4*)(gh + (size_t)gm * HD + n0 + 4) = *(float4*)&acc[r][4];
  }
}

// ------------------------------------------------------------------
// per-molecule energy reduction
// ------------------------------------------------------------------
__global__ __launch_bounds__(64) void ered_k(
    const int* __restrict__ batch, const float* __restrict__ ea,
    float* __restrict__ energy)
{
  int m = blockIdx.x;
  int lo = 0, hi = N_ATOMS;
  while (lo < hi) { int mid = (lo + hi) >> 1; if (batch[mid] < m) lo = mid + 1; else hi = mid; }
  int beg = lo;
  lo = beg; hi = N_ATOMS;
  while (lo < hi) { int mid = (lo + hi) >> 1; if (batch[mid] < m + 1) lo = mid + 1; else hi = mid; }
  int end = lo;
  float s = 0.0f;
  for (int i = beg + threadIdx.x; i < end; i += 64) s += ea[i];
#pragma unroll
  for (int off = 32; off > 0; off >>= 1) s += __shfl_down(s, off, 64);
  if (threadIdx.x == 0) energy[m] = s;
}

// ------------------------------------------------------------------
// force gather
// ------------------------------------------------------------------
__global__ __launch_bounds__(256) void forceg_k(
    const int* __restrict__ rptr, const int* __restrict__ rother,
    const float* __restrict__ rdist,
    const int* __restrict__ cptr, const int* __restrict__ cother,
    const float* __restrict__ cdist, const int* __restrict__ cslot,
    const float* __restrict__ ddslot, const float* __restrict__ pos,
    float* __restrict__ force)
{
  int idx = blockIdx.x * 256 + threadIdx.x;
  int a = idx >> 3;
  int g = idx & 7;
  if (a >= N_ATOMS) return;
  float px = pos[3*a+0], py = pos[3*a+1], pz = pos[3*a+2];
  float fx = 0.f, fy = 0.f, fz = 0.f;
  int beg = rptr[a], end = rptr[a+1];
  for (int j = beg + g; j < end; j += 8) {
    int o = rother[j];
    float w = ddslot[j] / rdist[j];
    fx -= w * (px - pos[3*o+0]);
    fy -= w * (py - pos[3*o+1]);
    fz -= w * (pz - pos[3*o+2]);
  }
  beg = cptr[a]; end = cptr[a+1];
  for (int j = beg + g; j < end; j += 8) {
    int o = cother[j];
    float w = ddslot[cslot[j]] / cdist[j];
    fx -= w * (px - pos[3*o+0]);
    fy -= w * (py - pos[3*o+1]);
    fz -= w * (pz - pos[3*o+2]);
  }
#pragma unroll
  for (int off = 4; off > 0; off >>= 1) {
    fx += __shfl_down(fx, off, 8);
    fy += __shfl_down(fy, off, 8);
    fz += __shfl_down(fz, off, 8);
  }
  if (g == 0) {
    force[3*a+0] = fx;
    force[3*a+1] = fy;
    force[3*a+2] = fz;
  }
}

// ------------------------------------------------------------------
// host launch
// ------------------------------------------------------------------
static inline int nblk(int m) { return (m + 63) / 64; }

extern "C" void kernel_launch(void* const* d_in, const int* in_sizes, int n_in,
                              void* d_out, int out_size, void* d_ws, size_t ws_size,
                              hipStream_t stream)
{
  const float* pos   = (const float*)d_in[0];
  const int*   z     = (const int*)d_in[1];
  const int*   batch = (const int*)d_in[2];
  const int*   eidx  = (const int*)d_in[3];
  const float* emb   = (const float*)d_in[4];
  const float* mlp_w1 = (const float*)d_in[5];
  const float* mlp_b1 = (const float*)d_in[6];
  const float* mlp_w2 = (const float*)d_in[7];
  const float* mlp_b2 = (const float*)d_in[8];
  const float* lin1_w = (const float*)d_in[9];
  const float* lin2_w = (const float*)d_in[10];
  const float* lin2_b = (const float*)d_in[11];
  const float* blk_w  = (const float*)d_in[12];
  const float* blk_b  = (const float*)d_in[13];
  const float* hw1 = (const float*)d_in[14];
  const float* hb1 = (const float*)d_in[15];
  const float* hw2 = (const float*)d_in[16];
  const float* hb2 = (const float*)d_in[17];

  float* out = (float*)d_out;          // [NMOL] energies ++ [N,3] forces
  float* ws  = (float*)d_ws;

  const int* row = eidx;
  const int* col = eidx + N_EDGES;

  const size_t NH = (size_t)N_ATOMS * HD;
  size_t o = 0;
  float* dist   = ws + o; o += N_EDGES;
  float* ddslot = ws + o; o += N_EDGES;
  int* cptr   = (int*)(ws + o); o += N_ATOMS + 1;
  int* rptr   = (int*)(ws + o); o += N_ATOMS + 1;
  int* cother = (int*)(ws + o); o += N_EDGES;
  int* rother = (int*)(ws + o); o += N_EDGES;
  int* slotof = (int*)(ws + o); o += N_EDGES;
  int* cslot  = (int*)(ws + o); o += N_EDGES;
  float* cdist = ws + o; o += N_EDGES;
  float* rdist = ws + o; o += N_EDGES;
  int* cur0   = (int*)(ws + o); o += N_ATOMS;
  int* cur1   = (int*)(ws + o); o += N_ATOMS;
  // bf16 weights: wt = transposed, wp = plain, mt = transposed mlp weights
  o = (o + 3) & ~(size_t)3;
  u16* wt = (u16*)(ws + o); o += (size_t)NLAY * 3 * HD * HD / 2;
  u16* wp = (u16*)(ws + o); o += (size_t)NLAY * 3 * HD * HD / 2;
  u16* mt = (u16*)(ws + o); o += (size_t)NLAY * 2 * HD * HD / 2;
  float* hxb[4];   // stored as bf16 (128 u16 per row)
  for (int i = 0; i < 4; i++) { hxb[i] = ws + o; o += NH; }
  float* vbuf[4];
  for (int i = 0; i < 4; i++) { vbuf[i] = ws + o; o += NH; }
  float* hA  = ws + o; o += NH;
  float* hB  = ws + o; o += NH;       // fwd h ping-pong; bwd: dv packed scratch
  float* agg = ws + o; o += NH;       // fwd agg / bwd dhx / table temps
  float* g0b = ws + o; o += NH;
  float* g1b = ws + o; o += NH;
  float* dgb = ws + o; o += NH;       // fwd: spk scratch / ea; bwd: dagg(bf16)

  // table: bf16 pairs, 1 uint per (node,ch)
  int NT = 1024;
  while (NT > 128) {
    size_t need = o + (size_t)NLAY * (NT + 1) * HD;
    if (need * sizeof(float) <= ws_size) break;
    NT >>= 1;
  }
  const int NN = NT + 1;
  const float hstep = FCUT / (float)NT;
  const float inv_h = (float)NT / FCUT;
  unsigned* T = (unsigned*)(ws + o); o += (size_t)NLAY * NN * HD;

  hipMemsetAsync(ddslot, 0, N_EDGES * sizeof(float), stream);

  geom_k<<<(N_EDGES + 255) / 256, 256, 0, stream>>>(pos, row, col, dist);
  wprep_k<<<(NLAY * 5 * HD * HD + 255) / 256, 256, 0, stream>>>(
      lin1_w, lin2_w, blk_w, mlp_w1, mlp_w2, wt, wp, mt);

  // ---------------- CSR build (both directions) ----------------
  {
    const int EB = (N_EDGES + 255) / 256;
    hipMemsetAsync(cur0, 0, N_ATOMS * sizeof(int), stream);
    hipMemsetAsync(cur1, 0, N_ATOMS * sizeof(int), stream);
    hist_k<<<EB, 256, 0, stream>>>(col, cur0);
    hist_k<<<EB, 256, 0, stream>>>(row, cur1);
    scan_k<<<1, 256, 0, stream>>>(cur0, cptr);
    scan_k<<<1, 256, 0, stream>>>(cur1, rptr);
    hipMemcpyAsync(cur0, cptr, N_ATOMS * sizeof(int), hipMemcpyDeviceToDevice, stream);
    hipMemcpyAsync(cur1, rptr, N_ATOMS * sizeof(int), hipMemcpyDeviceToDevice, stream);
    scat_row_k<<<EB, 256, 0, stream>>>(row, col, dist, cur1, rother, rdist, slotof);
    scat_col_k<<<EB, 256, 0, stream>>>(row, col, dist, cur0, cother, cdist, slotof, cslot);
  }

  // ---------------- build filter tables (all 4 layers) ----------------
  {
    const size_t LNH = (size_t)NN * HD;
    float* Anode  = agg;
    float* dAnode = agg + LNH;
    float* t1 = dgb;
    float* u  = g0b;
    float* s  = g1b;
    float* sp = hA;
    nodeA_k<<<((int)LNH + 255) / 256, 256, 0, stream>>>(Anode, dAnode, NN, hstep);
    dim3 gB16((NN + 15) / 16, NLAY);
    tblmm_k<<<gB16, 256, 0, stream>>>(Anode, 0, mt, 32768,
                                      mlp_b1, HD, t1, LNH, NN);
    tblmm_k<<<gB16, 256, 0, stream>>>(dAnode, 0, mt, 32768,
                                      nullptr, 0, u, LNH, NN);
    int tot = (int)(NLAY * LNH);
    nodeact_k<<<(tot + 255) / 256, 256, 0, stream>>>(t1, u, s, sp, tot);
    float* P0 = dgb;
    float* D0 = g0b;
    tblmm_k<<<gB16, 256, 0, stream>>>(s, LNH, mt + 16384, 32768,
                                      mlp_b2, HD, P0, LNH, NN);
    tblmm_k<<<gB16, 256, 0, stream>>>(sp, LNH, mt + 16384, 32768,
                                      nullptr, 0, D0, LNH, NN);
    nodecomb_k<<<(tot + 255) / 256, 256, 0, stream>>>(P0, D0, T, NN, hstep);
  }

  h0_k<<<(N_ATOMS * HD + 255) / 256, 256, 0, stream>>>(emb, z, hA);

  const int AB = (N_ATOMS + 3) / 4;
  const int GB = nblk(N_ATOMS);
  const int NB16 = (N_ATOMS + 15) / 16;   // 1250 blocks for no-LDS MFMA GEMMs

  // ---------------- forward ----------------
  float* hcur = hA;
  float* hnxt = hB;
  for (int i = 0; i < NLAY; i++) {
    const u16* l1t = wt + ((size_t)(i*3 + 0) << 14);
    const u16* l2t = wt + ((size_t)(i*3 + 1) << 14);
    const u16* bwt = wt + ((size_t)(i*3 + 2) << 14);
    const float* l2bi = lin2_b + (size_t)i * HD;
    const float* bbi  = blk_b + (size_t)i * HD;
    const unsigned* Tl = T + (size_t)i * NN * HD;

    nmm_hx_k<<<NB16, 256, 0, stream>>>(hcur, l1t, (u16*)hxb[i], N_ATOMS);
    gath_fwd_k<<<AB, 256, 0, stream>>>(cptr, cother, cdist, Tl, (const unsigned*)hxb[i], agg, inv_h, hstep);
    ftail1_k<<<NB16, 256, 0, stream>>>(agg, l2t, l2bi, vbuf[i], (unsigned*)dgb, N_ATOMS);
    ftail2_k<<<NB16, 256, 0, stream>>>((const unsigned*)dgb, bwt, bbi, hcur, hnxt, N_ATOMS);
    float* tmp = hcur; hcur = hnxt; hnxt = tmp;
  }

  // ---------------- head (fused) + per-molecule energy ----------------
  // NLAY even -> hcur == hA here; hB free for bwd scratch
  float* ea = dgb;
  headf_k<<<GB, 256, 0, stream>>>(hcur, hw1, hb1, hw2, hb2, ea, g0b);
  ered_k<<<NMOL, 64, 0, stream>>>(batch, ea, out);

  // ---------------- backward ----------------
  float* gcur = g0b;
  float* gnxt = g1b;
  unsigned* dvpk = (unsigned*)hB;
  for (int i = NLAY - 1; i >= 0; i--) {
    const u16* l1p = wp + ((size_t)(i*3 + 0) << 14);
    const u16* l2p = wp + ((size_t)(i*3 + 1) << 14);
    const u16* bwp = wp + ((size_t)(i*3 + 2) << 14);
    const unsigned* Tl = T + (size_t)i * NN * HD;

    bhead1_k<<<NB16, 256, 0, stream>>>(gcur, bwp, vbuf[i], dvpk, N_ATOMS);
    bhead2_k<<<NB16, 256, 0, stream>>>(dvpk, l2p, (u16*)dgb, N_ATOMS);
    gath_bwd_k<<<AB, 256, 0, stream>>>(rptr, rother, rdist, Tl, (const unsigned*)dgb,
                                       (const unsigned*)hxb[i], agg, ddslot, inv_h, hstep);
    if (i > 0) {
      nmm_bwdT_k<<<NB16, 256, 0, stream>>>(agg, l1p, gcur, gnxt, N_ATOMS);
      float* tmp = gcur; gcur = gnxt; gnxt = tmp;
    }
  }

  forceg_k<<<(N_ATOMS * 8 + 255) / 256, 256, 0, stream>>>(
      rptr, rother, rdist, cptr, cother, cdist, cslot, ddslot, pos, out + NMOL);
}

// Round 4
// 887.919 us; speedup vs baseline: 1.3181x; 1.1108x over previous
//
#include <hip/hip_runtime.h>

#define HD 128

constexpr int N_ATOMS = 20000;
constexpr int N_EDGES = 320000;
constexpr int NLAY   = 4;
constexpr int NMOL   = 200;
constexpr float FCUT  = 5.0f;
constexpr float DELTA = FCUT / 127.0f;
constexpr float GCOEFF = -0.5f / (DELTA * DELTA);
constexpr float PI_F  = 3.14159265358979323846f;
constexpr float LN2F  = 0.6931471805599453f;

typedef unsigned short u16;
typedef __attribute__((ext_vector_type(8))) short short8v;
typedef __attribute__((ext_vector_type(4))) float f32x4;

__device__ __forceinline__ float sspf(float x) {
  return fmaxf(x, 0.0f) + log1pf(expf(-fabsf(x))) - LN2F;
}
__device__ __forceinline__ float sigmf(float x) {
  return 1.0f / (1.0f + expf(-x));
}

// bf16 pack/unpack (round-to-nearest-even)
__device__ __forceinline__ unsigned bfpack(float a, float b) {
  unsigned ua = __float_as_uint(a);
  unsigned ub = __float_as_uint(b);
  ua = (ua + 0x7FFFu + ((ua >> 16) & 1u)) >> 16;
  ub = (ub + 0x7FFFu + ((ub >> 16) & 1u)) >> 16;
  return (ub << 16) | ua;
}
__device__ __forceinline__ float bflo(unsigned p) { return __uint_as_float(p << 16); }
__device__ __forceinline__ float bfhi(unsigned p) { return __uint_as_float(p & 0xFFFF0000u); }
__device__ __forceinline__ u16 f2bf(float x) {
  unsigned u = __float_as_uint(x);
  u = (u + 0x7FFFu + ((u >> 16) & 1u)) >> 16;
  return (u16)u;
}
__device__ __forceinline__ float bf2f(u16 b) { return __uint_as_float((unsigned)b << 16); }

// split f32 into hi bf16 (truncate) + lo bf16, packed u32 (hi<<16 | lo)
__device__ __forceinline__ unsigned packhl(float s) {
  unsigned hs = __float_as_uint(s) & 0xffff0000u;
  float lo = s - __uint_as_float(hs);
  return hs | (__float_as_uint(lo) >> 16);
}

// two f32 bit patterns -> hi-pair uint and lo-pair uint (bf16 pairs)
__device__ __forceinline__ unsigned hpair_f32(unsigned a, unsigned b, unsigned& lopair) {
  unsigned ha = a & 0xffff0000u, hb = b & 0xffff0000u;
  float la = __uint_as_float(a) - __uint_as_float(ha);
  float lb = __uint_as_float(b) - __uint_as_float(hb);
  lopair = (__float_as_uint(lb) & 0xffff0000u) | (__float_as_uint(la) >> 16);
  return hb | (ha >> 16);
}

// ------------------------------------------------------------------
// small elementwise kernels
// ------------------------------------------------------------------

__global__ __launch_bounds__(256) void h0_k(
    const float* __restrict__ emb, const int* __restrict__ z,
    float* __restrict__ h0)
{
  int i = blockIdx.x * 256 + threadIdx.x;
  if (i >= N_ATOMS * HD) return;
  int n = i >> 7, k = i & 127;
  h0[i] = emb[z[n] * HD + k];
}

// bf16 weight prep:
//  wsel 0..2 (lin1,lin2,blk): wp = bf16(W) row-major, wt = bf16(W^T)
//  wsel 3..4 (mlp_w1,mlp_w2): mt = bf16(W^T) only
__global__ __launch_bounds__(256) void wprep_k(
    const float* __restrict__ l1, const float* __restrict__ l2,
    const float* __restrict__ bw, const float* __restrict__ mw1,
    const float* __restrict__ mw2,
    u16* __restrict__ wt, u16* __restrict__ wp, u16* __restrict__ mt)
{
  int i = blockIdx.x * 256 + threadIdx.x;
  if (i >= NLAY * 5 * HD * HD) return;
  int e = i & (HD * HD - 1);
  int wl = i >> 14;
  int wsel = wl % 5;
  int lay = wl / 5;
  const float* W;
  if      (wsel == 0) W = l1;
  else if (wsel == 1) W = l2;
  else if (wsel == 2) W = bw;
  else if (wsel == 3) W = mw1;
  else                W = mw2;
  W += (size_t)lay * HD * HD;
  u16 b = f2bf(W[e]);
  int k = e >> 7, n = e & 127;
  if (wsel < 3) {
    size_t base = (size_t)(lay * 3 + wsel) << 14;
    wp[base + e] = b;
    wt[base + (size_t)n * HD + k] = b;
  } else {
    size_t base = (size_t)(lay * 2 + (wsel - 3)) << 14;
    mt[base + (size_t)n * HD + k] = b;
  }
}

// ------------------------------------------------------------------
// CSR build: combined histogram, dual scan, combined scatter+geom+coef
// ------------------------------------------------------------------
__global__ __launch_bounds__(256) void histboth_k(
    const int* __restrict__ row, const int* __restrict__ col,
    int* __restrict__ cntR, int* __restrict__ cntC)
{
  int e = blockIdx.x * 256 + threadIdx.x;
  if (e >= N_EDGES) return;
  atomicAdd(&cntC[col[e]], 1);
  atomicAdd(&cntR[row[e]], 1);
}

// block 0: cnt0 -> cptr,cur0 ; block 1: cnt1 -> rptr,cur1
__global__ __launch_bounds__(256) void scan2_k(
    const int* __restrict__ cnt0, const int* __restrict__ cnt1,
    int* __restrict__ cptr, int* __restrict__ rptr,
    int* __restrict__ cur0, int* __restrict__ cur1)
{
  constexpr int CH = 79;  // 256*79 = 20224 >= 20001
  __shared__ int part[256];
  const int* cnt = blockIdx.x == 0 ? cnt0 : cnt1;
  int* ptr = blockIdx.x == 0 ? cptr : rptr;
  int* cur = blockIdx.x == 0 ? cur0 : cur1;
  int t = threadIdx.x;
  int base = t * CH;
  int s = 0;
  for (int i = 0; i < CH; i++) {
    int idx = base + i;
    if (idx < N_ATOMS) s += cnt[idx];
  }
  part[t] = s;
  __syncthreads();
  for (int off = 1; off < 256; off <<= 1) {
    int u = (t >= off) ? part[t - off] : 0;
    __syncthreads();
    part[t] += u;
    __syncthreads();
  }
  int run = part[t] - s;
  for (int i = 0; i < CH; i++) {
    int idx = base + i;
    if (idx > N_ATOMS) break;
    ptr[idx] = run;
    if (idx < N_ATOMS) { cur[idx] = run; run += cnt[idx]; }
  }
}

// geometry + Hermite coefficients + both-direction CSR scatter, one pass
__global__ __launch_bounds__(256) void scatboth_k(
    const float* __restrict__ pos, const int* __restrict__ row,
    const int* __restrict__ col, int* __restrict__ cur0,
    int* __restrict__ cur1, unsigned* __restrict__ cpk,
    unsigned* __restrict__ rpk, float* __restrict__ cdist,
    float* __restrict__ rdist, float4* __restrict__ ccoef,
    float4* __restrict__ rcoefA, float4* __restrict__ rcoefB,
    int* __restrict__ cslot, float inv_h, float hstep)
{
  int e = blockIdx.x * 256 + threadIdx.x;
  if (e >= N_EDGES) return;
  int r = row[e], c = col[e];
  float dx = pos[3*r+0] - pos[3*c+0];
  float dy = pos[3*r+1] - pos[3*c+1];
  float dz = pos[3*r+2] - pos[3*c+2];
  float d = sqrtf(dx*dx + dy*dy + dz*dz);
  float fi = d * inv_h;
  int i0 = (int)fi;
  float t = fi - (float)i0;
  float t2 = t * t, t3 = t2 * t;
  float a00 = 2.f*t3 - 3.f*t2 + 1.f;
  float a10 = (t3 - 2.f*t2 + t) * hstep;
  float a01 = 3.f*t2 - 2.f*t3;
  float a11 = (t3 - t2) * hstep;
  float b00 = (6.f*t2 - 6.f*t) * inv_h;
  float b10 = 3.f*t2 - 4.f*t + 1.f;
  float b01 = -b00;
  float b11 = 3.f*t2 - 2.f*t;
  int pr = atomicAdd(&cur1[r], 1);
  rpk[pr] = (unsigned)c | ((unsigned)i0 << 16);
  rdist[pr] = d;
  rcoefA[pr] = make_float4(a00, a10, a01, a11);
  rcoefB[pr] = make_float4(b00, b10, b01, b11);
  int pc = atomicAdd(&cur0[c], 1);
  cpk[pc] = (unsigned)r | ((unsigned)i0 << 16);
  cdist[pc] = d;
  ccoef[pc] = make_float4(a00, a10, a01, a11);
  cslot[pc] = pr;
}

// ------------------------------------------------------------------
// table build
// ------------------------------------------------------------------
__global__ __launch_bounds__(256) void nodeA_k(
    float* __restrict__ A, float* __restrict__ dA, int nnode, float hstep)
{
  int i = blockIdx.x * 256 + threadIdx.x;
  if (i >= nnode * HD) return;
  int node = i >> 7, g = i & 127;
  float d = (float)node * hstep;
  float t = d - (float)g * DELTA;
  float a = expf(GCOEFF * t * t);
  A[i] = a;
  dA[i] = a * 2.0f * GCOEFF * t;
}

__global__ __launch_bounds__(256) void nodeact_k(
    const float* __restrict__ t1, const float* __restrict__ u,
    float* __restrict__ s, float* __restrict__ sp, int total)
{
  int i = blockIdx.x * 256 + threadIdx.x;
  if (i >= total) return;
  float x = t1[i];
  s[i] = sspf(x);
  sp[i] = sigmf(x) * u[i];
}

__global__ __launch_bounds__(256) void nodecomb_k(
    const float* __restrict__ P0, const float* __restrict__ D0,
    unsigned* __restrict__ T, int nnode, float hstep)
{
  int i = blockIdx.x * 256 + threadIdx.x;
  int total = NLAY * nnode * HD;
  if (i >= total) return;
  int rem = i % (nnode * HD);
  int node = rem >> 7;
  float d = (float)node * hstep;
  float C  = 0.5f * cosf(d * (PI_F / FCUT)) + 0.5f;
  float Cp = -0.5f * sinf(d * (PI_F / FCUT)) * (PI_F / FCUT);
  float p = P0[i], q = D0[i];
  T[i] = bfpack(p * C, q * C + p * Cp);
}

// ------------------------------------------------------------------
// no-LDS MFMA wave GEMM: wave computes rows [m0,m0+16) x cols
// [wbase,wbase+32) of C = A[M,128] @ B[128,128].
// Bt layout: Bt[n*HD + k] = B[k][n] (bf16).
// A per-lane from global (lane -> row lane&15, k-octet (lane>>4)*8),
// split hi/lo bf16 in registers. No LDS, no barriers.
// ------------------------------------------------------------------
__device__ __forceinline__ void wave_mm(
    const float* __restrict__ Av, const u16* __restrict__ Bt,
    int m0, int wbase, int lc, int lg, int mclamp, f32x4 acc[2])
{
  short8v bfr[4][2];
#pragma unroll
  for (int ks = 0; ks < 4; ++ks)
#pragma unroll
    for (int nt = 0; nt < 2; ++nt)
      bfr[ks][nt] = *(const short8v*)(Bt + (size_t)(wbase + nt*16 + lc) * HD + ks*32 + lg*8);
  int ar = m0 + lc;
  if (ar > mclamp) ar = mclamp;   // row-clamped load; garbage rows never stored
  f32x4 z = {0.f, 0.f, 0.f, 0.f};
  acc[0] = z; acc[1] = z;
#pragma unroll
  for (int ks = 0; ks < 4; ++ks) {
    const float* p = Av + (size_t)ar * HD + ks*32 + lg*8;
    uint4 u0 = *(const uint4*)p;
    uint4 u1 = *(const uint4*)(p + 4);
    unsigned p0l, p1l, p2l, p3l;
    unsigned p0h = hpair_f32(u0.x, u0.y, p0l);
    unsigned p1h = hpair_f32(u0.z, u0.w, p1l);
    unsigned p2h = hpair_f32(u1.x, u1.y, p2l);
    unsigned p3h = hpair_f32(u1.z, u1.w, p3l);
    uint4 hv = make_uint4(p0h, p1h, p2h, p3h);
    uint4 lv = make_uint4(p0l, p1l, p2l, p3l);
    short8v ah = *(short8v*)&hv, al = *(short8v*)&lv;
    acc[0] = __builtin_amdgcn_mfma_f32_16x16x32_bf16(ah, bfr[ks][0], acc[0], 0, 0, 0);
    acc[1] = __builtin_amdgcn_mfma_f32_16x16x32_bf16(ah, bfr[ks][1], acc[1], 0, 0, 0);
    acc[0] = __builtin_amdgcn_mfma_f32_16x16x32_bf16(al, bfr[ks][0], acc[0], 0, 0, 0);
    acc[1] = __builtin_amdgcn_mfma_f32_16x16x32_bf16(al, bfr[ks][1], acc[1], 0, 0, 0);
  }
}

// same, A from LDS tile of packed (hi16|lo16) u32, rows [16][132]
__device__ __forceinline__ void wave_mm_lds(
    const unsigned (*__restrict__ Sl)[132], const u16* __restrict__ Bt,
    int wbase, int lc, int lg, f32x4 acc[2])
{
  short8v bfr[4][2];
#pragma unroll
  for (int ks = 0; ks < 4; ++ks)
#pragma unroll
    for (int nt = 0; nt < 2; ++nt)
      bfr[ks][nt] = *(const short8v*)(Bt + (size_t)(wbase + nt*16 + lc) * HD + ks*32 + lg*8);
  f32x4 z = {0.f, 0.f, 0.f, 0.f};
  acc[0] = z; acc[1] = z;
#pragma unroll
  for (int ks = 0; ks < 4; ++ks) {
    uint4 u0 = *(const uint4*)&Sl[lc][ks*32 + lg*8];
    uint4 u1 = *(const uint4*)&Sl[lc][ks*32 + lg*8 + 4];
    uint4 hv = make_uint4(
      (u0.y & 0xffff0000u) | (u0.x >> 16),
      (u0.w & 0xffff0000u) | (u0.z >> 16),
      (u1.y & 0xffff0000u) | (u1.x >> 16),
      (u1.w & 0xffff0000u) | (u1.z >> 16));
    uint4 lv = make_uint4(
      (u0.y << 16) | (u0.x & 0xffffu),
      (u0.w << 16) | (u0.z & 0xffffu),
      (u1.y << 16) | (u1.x & 0xffffu),
      (u1.w << 16) | (u1.z & 0xffffu));
    short8v ah = *(short8v*)&hv, al = *(short8v*)&lv;
    acc[0] = __builtin_amdgcn_mfma_f32_16x16x32_bf16(ah, bfr[ks][0], acc[0], 0, 0, 0);
    acc[1] = __builtin_amdgcn_mfma_f32_16x16x32_bf16(ah, bfr[ks][1], acc[1], 0, 0, 0);
    acc[0] = __builtin_amdgcn_mfma_f32_16x16x32_bf16(al, bfr[ks][0], acc[0], 0, 0, 0);
    acc[1] = __builtin_amdgcn_mfma_f32_16x16x32_bf16(al, bfr[ks][1], acc[1], 0, 0, 0);
  }
}

// hx = h @ W  (Bt = W^T bf16), output u16 bf16
__global__ __launch_bounds__(256) void nmm_hx_k(
    const float* __restrict__ h, const u16* __restrict__ Bt,
    u16* __restrict__ hx, int M)
{
  int t = threadIdx.x, lane = t & 63;
  int lc = lane & 15, lg = lane >> 4;
  int wbase = (t >> 6) * 32;
  int m0 = blockIdx.x * 16;
  f32x4 acc[2];
  wave_mm(h, Bt, m0, wbase, lc, lg, M - 1, acc);
#pragma unroll
  for (int nt = 0; nt < 2; ++nt) {
    int ccol = wbase + nt*16 + lc;
#pragma unroll
    for (int j = 0; j < 4; ++j) {
      int grow = m0 + lg*4 + j;
      if (grow < M) hx[(size_t)grow * HD + ccol] = f2bf(acc[nt][j]);
    }
  }
}

// C = A @ W^T + addin  (Bp = W bf16 row-major), fp32 out
__global__ __launch_bounds__(256) void nmm_bwdT_k(
    const float* __restrict__ A, const u16* __restrict__ Bp,
    const float* __restrict__ addin, float* __restrict__ C, int M)
{
  int t = threadIdx.x, lane = t & 63;
  int lc = lane & 15, lg = lane >> 4;
  int wbase = (t >> 6) * 32;
  int m0 = blockIdx.x * 16;
  f32x4 acc[2];
  wave_mm(A, Bp, m0, wbase, lc, lg, M - 1, acc);
#pragma unroll
  for (int nt = 0; nt < 2; ++nt) {
    int ccol = wbase + nt*16 + lc;
#pragma unroll
    for (int j = 0; j < 4; ++j) {
      int grow = m0 + lg*4 + j;
      if (grow < M)
        C[(size_t)grow * HD + ccol] = acc[nt][j] + addin[(size_t)grow * HD + ccol];
    }
  }
}

// fused fwd tail: V = agg@l2 + l2b; svb = bf16(sigm(V));
// hout = h + ssp(V)@bw + bb.  ssp(V) passed via 16x132 LDS hi/lo tile.
__global__ __launch_bounds__(256) void ftail_f_k(
    const float* __restrict__ agg, const u16* __restrict__ l2t,
    const float* __restrict__ l2b, const u16* __restrict__ bwt,
    const float* __restrict__ bb, const float* __restrict__ h,
    u16* __restrict__ svb, float* __restrict__ hout, int M)
{
  __shared__ unsigned Sl[16][132];
  int t = threadIdx.x, lane = t & 63;
  int lc = lane & 15, lg = lane >> 4;
  int wbase = (t >> 6) * 32;
  int m0 = blockIdx.x * 16;
  f32x4 acc[2];
  wave_mm(agg, l2t, m0, wbase, lc, lg, M - 1, acc);
#pragma unroll
  for (int nt = 0; nt < 2; ++nt) {
    int ccol = wbase + nt*16 + lc;
    float bv = l2b[ccol];
#pragma unroll
    for (int j = 0; j < 4; ++j) {
      int lrow = lg*4 + j;
      int grow = m0 + lrow;
      float s = 0.0f;
      if (grow < M) {
        float x = acc[nt][j] + bv;
        svb[(size_t)grow * HD + ccol] = f2bf(sigmf(x));
        s = sspf(x);
      }
      Sl[lrow][ccol] = packhl(s);
    }
  }
  __syncthreads();
  wave_mm_lds(Sl, bwt, wbase, lc, lg, acc);
#pragma unroll
  for (int nt = 0; nt < 2; ++nt) {
    int ccol = wbase + nt*16 + lc;
    float bv = bb[ccol];
#pragma unroll
    for (int j = 0; j < 4; ++j) {
      int grow = m0 + lg*4 + j;
      if (grow < M)
        hout[(size_t)grow * HD + ccol] =
            acc[nt][j] + bv + h[(size_t)grow * HD + ccol];
    }
  }
}

// fused bwd head: dv = (g@bw^T)*sigm(V) (from svb); dagg = dv@l2^T (bf16)
__global__ __launch_bounds__(256) void bhead_f_k(
    const float* __restrict__ g, const u16* __restrict__ bwp,
    const u16* __restrict__ svb, const u16* __restrict__ l2p,
    u16* __restrict__ dagg, int M)
{
  __shared__ unsigned Sl[16][132];
  int t = threadIdx.x, lane = t & 63;
  int lc = lane & 15, lg = lane >> 4;
  int wbase = (t >> 6) * 32;
  int m0 = blockIdx.x * 16;
  f32x4 acc[2];
  wave_mm(g, bwp, m0, wbase, lc, lg, M - 1, acc);
#pragma unroll
  for (int nt = 0; nt < 2; ++nt) {
    int ccol = wbase + nt*16 + lc;
#pragma unroll
    for (int j = 0; j < 4; ++j) {
      int lrow = lg*4 + j;
      int grow = m0 + lrow;
      float dv = 0.0f;
      if (grow < M)
        dv = acc[nt][j] * bf2f(svb[(size_t)grow * HD + ccol]);
      Sl[lrow][ccol] = packhl(dv);
    }
  }
  __syncthreads();
  wave_mm_lds(Sl, l2p, wbase, lc, lg, acc);
#pragma unroll
  for (int nt = 0; nt < 2; ++nt) {
    int ccol = wbase + nt*16 + lc;
#pragma unroll
    for (int j = 0; j < 4; ++j) {
      int grow = m0 + lg*4 + j;
      if (grow < M) dagg[(size_t)grow * HD + ccol] = f2bf(acc[nt][j]);
    }
  }
}

// batched table-build GEMM; blockIdx.z selects (A0,bias0,C0) or (A1,null,C1)
__global__ __launch_bounds__(256) void tblmm2_k(
    const float* __restrict__ A0, const float* __restrict__ A1, size_t astride,
    const u16* __restrict__ Bt, size_t bstride,
    const float* __restrict__ bias0, size_t biasstride,
    float* __restrict__ C0, float* __restrict__ C1, size_t cstride, int M)
{
  int l = blockIdx.y;
  int zz = blockIdx.z;
  const float* A = (zz ? A1 : A0) + (size_t)l * astride;
  const u16* B = Bt + (size_t)l * bstride;
  const float* bias = zz ? nullptr : (bias0 ? bias0 + (size_t)l * biasstride : nullptr);
  float* C = (zz ? C1 : C0) + (size_t)l * cstride;
  int t = threadIdx.x, lane = t & 63;
  int lc = lane & 15, lg = lane >> 4;
  int wbase = (t >> 6) * 32;
  int m0 = blockIdx.x * 16;
  f32x4 acc[2];
  wave_mm(A, B, m0, wbase, lc, lg, M - 1, acc);
#pragma unroll
  for (int nt = 0; nt < 2; ++nt) {
    int ccol = wbase + nt*16 + lc;
    float bv = bias ? bias[ccol] : 0.0f;
#pragma unroll
    for (int j = 0; j < 4; ++j) {
      int grow = m0 + lg*4 + j;
      if (grow < M) C[(size_t)grow * HD + ccol] = acc[nt][j] + bv;
    }
  }
}

// ------------------------------------------------------------------
// forward gather: agg[a] = sum_in hx[src] * P(d); precomputed coeffs
// ------------------------------------------------------------------
__global__ __launch_bounds__(256) void gath_fwd_k(
    const int* __restrict__ cptr, const unsigned* __restrict__ cpk,
    const float4* __restrict__ ccoef, const unsigned* __restrict__ T,
    const unsigned* __restrict__ hx, float* __restrict__ agg)
{
  int a = blockIdx.x * 4 + (threadIdx.x >> 6);
  if (a >= N_ATOMS) return;
  int half = (threadIdx.x >> 5) & 1;
  int l32 = threadIdx.x & 31;
  int ch = l32 * 4;
  int beg = cptr[a], end = cptr[a + 1];
  float s0 = 0.f, s1 = 0.f, s2 = 0.f, s3 = 0.f;
#pragma unroll 2
  for (int j = beg + half; j < end; j += 2) {
    unsigned pk = cpk[j];
    float4 cf = ccoef[j];
    int other = pk & 0xffffu;
    const unsigned* tp = T + (size_t)(pk >> 16) * HD + ch;
    uint4 q0 = *(const uint4*)(tp);
    uint4 q1 = *(const uint4*)(tp + HD);
    uint2 hp = *(const uint2*)(hx + (size_t)other * 64 + l32 * 2);
    float v0 = cf.x*bflo(q0.x) + cf.y*bfhi(q0.x) + cf.z*bflo(q1.x) + cf.w*bfhi(q1.x);
    float v1 = cf.x*bflo(q0.y) + cf.y*bfhi(q0.y) + cf.z*bflo(q1.y) + cf.w*bfhi(q1.y);
    float v2 = cf.x*bflo(q0.z) + cf.y*bfhi(q0.z) + cf.z*bflo(q1.z) + cf.w*bfhi(q1.z);
    float v3 = cf.x*bflo(q0.w) + cf.y*bfhi(q0.w) + cf.z*bflo(q1.w) + cf.w*bfhi(q1.w);
    s0 = fmaf(bflo(hp.x), v0, s0);
    s1 = fmaf(bfhi(hp.x), v1, s1);
    s2 = fmaf(bflo(hp.y), v2, s2);
    s3 = fmaf(bfhi(hp.y), v3, s3);
  }
  s0 += __shfl_xor(s0, 32, 64);
  s1 += __shfl_xor(s1, 32, 64);
  s2 += __shfl_xor(s2, 32, 64);
  s3 += __shfl_xor(s3, 32, 64);
  if (half == 0)
    *(float4*)(agg + (size_t)a * HD + ch) = make_float4(s0, s1, s2, s3);
}

// ------------------------------------------------------------------
// backward gather: dhx + per-edge ddslot accumulation
// ------------------------------------------------------------------
__global__ __launch_bounds__(256) void gath_bwd_k(
    const int* __restrict__ rptr, const unsigned* __restrict__ rpk,
    const float4* __restrict__ rcoefA, const float4* __restrict__ rcoefB,
    const unsigned* __restrict__ T, const unsigned* __restrict__ dagg,
    const unsigned* __restrict__ hx, float* __restrict__ dhx,
    float* __restrict__ ddslot)
{
  int a = blockIdx.x * 4 + (threadIdx.x >> 6);
  if (a >= N_ATOMS) return;
  int half = (threadIdx.x >> 5) & 1;
  int l32 = threadIdx.x & 31;
  int ch = l32 * 4;
  int beg = rptr[a], end = rptr[a + 1];
  uint2 hp = *(const uint2*)(hx + (size_t)a * 64 + l32 * 2);
  float h0 = bflo(hp.x), h1 = bfhi(hp.x), h2 = bflo(hp.y), h3 = bfhi(hp.y);
  float s0 = 0.f, s1 = 0.f, s2 = 0.f, s3 = 0.f;
#pragma unroll 2
  for (int j = beg + half; j < end; j += 2) {
    unsigned pk = rpk[j];
    float4 ca = rcoefA[j];
    float4 cb = rcoefB[j];
    int other = pk & 0xffffu;
    const unsigned* tp = T + (size_t)(pk >> 16) * HD + ch;
    uint4 q0 = *(const uint4*)(tp);
    uint4 q1 = *(const uint4*)(tp + HD);
    uint2 dp = *(const uint2*)(dagg + (size_t)other * 64 + l32 * 2);
    float da0 = bflo(dp.x), da1 = bfhi(dp.x), da2 = bflo(dp.y), da3 = bfhi(dp.y);
    float x0l = bflo(q0.x), x0h = bfhi(q0.x), y0l = bflo(q1.x), y0h = bfhi(q1.x);
    float x1l = bflo(q0.y), x1h = bfhi(q0.y), y1l = bflo(q1.y), y1h = bfhi(q1.y);
    float x2l = bflo(q0.z), x2h = bfhi(q0.z), y2l = bflo(q1.z), y2h = bfhi(q1.z);
    float x3l = bflo(q0.w), x3h = bfhi(q0.w), y3l = bflo(q1.w), y3h = bfhi(q1.w);
    float v0 = ca.x*x0l + ca.y*x0h + ca.z*y0l + ca.w*y0h;
    float v1 = ca.x*x1l + ca.y*x1h + ca.z*y1l + ca.w*y1h;
    float v2 = ca.x*x2l + ca.y*x2h + ca.z*y2l + ca.w*y2h;
    float v3 = ca.x*x3l + ca.y*x3h + ca.z*y3l + ca.w*y3h;
    float g0 = cb.x*x0l + cb.y*x0h + cb.z*y0l + cb.w*y0h;
    float g1 = cb.x*x1l + cb.y*x1h + cb.z*y1l + cb.w*y1h;
    float g2 = cb.x*x2l + cb.y*x2h + cb.z*y2l + cb.w*y2h;
    float g3 = cb.x*x3l + cb.y*x3h + cb.z*y3l + cb.w*y3h;
    s0 = fmaf(da0, v0, s0);
    s1 = fmaf(da1, v1, s1);
    s2 = fmaf(da2, v2, s2);
    s3 = fmaf(da3, v3, s3);
    float dot = da0*h0*g0 + da1*h1*g1 + da2*h2*g2 + da3*h3*g3;
#pragma unroll
    for (int off = 16; off > 0; off >>= 1) dot += __shfl_down(dot, off, 32);
    if (l32 == 0) ddslot[j] += dot;
  }
  s0 += __shfl_xor(s0, 32, 64);
  s1 += __shfl_xor(s1, 32, 64);
  s2 += __shfl_xor(s2, 32, 64);
  s3 += __shfl_xor(s3, 32, 64);
  if (half == 0)
    *(float4*)(dhx + (size_t)a * HD + ch) = make_float4(s0, s1, s2, s3);
}

// ------------------------------------------------------------------
// fused head: s = h4@hw1 + hb1; ea[a] = ssp(s)@hw2 + hb2;
// gh = (sigm(s)*hw2) @ hw1^T
// ------------------------------------------------------------------
__global__ __launch_bounds__(256) void headf_k(
    const float* __restrict__ h4, const float* __restrict__ hw1,
    const float* __restrict__ hb1, const float* __restrict__ hw2,
    const float* __restrict__ hb2, float* __restrict__ ea,
    float* __restrict__ gh)
{
  __shared__ float As[16][68];
  __shared__ float Bs[16][132];
  __shared__ float Ss[64][68];
  __shared__ float red[64][17];
  int t = threadIdx.x;
  int tx = t & 15, ty = t >> 4;
  int m0 = blockIdx.x * 64;

  float acc4[4][4];
#pragma unroll
  for (int r = 0; r < 4; r++)
#pragma unroll
    for (int c = 0; c < 4; c++) acc4[r][c] = 0.0f;

  for (int k0 = 0; k0 < HD; k0 += 16) {
    {
      int rrow = t >> 2;
      int kg = (t & 3) * 4;
      int gm = m0 + rrow;
      float4 av = make_float4(0.f, 0.f, 0.f, 0.f);
      if (gm < N_ATOMS) av = *(const float4*)(h4 + (size_t)gm * HD + k0 + kg);
      As[kg+0][rrow] = av.x; As[kg+1][rrow] = av.y;
      As[kg+2][rrow] = av.z; As[kg+3][rrow] = av.w;
    }
    if (t < 256) {
      int kk = t >> 4;
      int n4 = (t & 15) * 4;
      float4 bv = *(const float4*)(hw1 + (size_t)(k0 + kk) * 64 + n4);
      *(float4*)&Bs[kk][n4] = bv;
    }
    __syncthreads();
#pragma unroll
    for (int kk = 0; kk < 16; kk++) {
      float a[4], b[4];
#pragma unroll
      for (int r = 0; r < 4; r++) a[r] = As[kk][ty * 4 + r];
#pragma unroll
      for (int c = 0; c < 4; c++) b[c] = Bs[kk][tx * 4 + c];
#pragma unroll
      for (int r = 0; r < 4; r++)
#pragma unroll
        for (int c = 0; c < 4; c++) acc4[r][c] = fmaf(a[r], b[c], acc4[r][c]);
    }
    __syncthreads();
  }

  {
    int n0 = tx * 4;
    float b1v[4], w2v[4];
#pragma unroll
    for (int c = 0; c < 4; c++) { b1v[c] = hb1[n0 + c]; w2v[c] = hw2[n0 + c]; }
#pragma unroll
    for (int r = 0; r < 4; r++) {
      int lr = ty * 4 + r;
      float p = 0.0f;
#pragma unroll
      for (int c = 0; c < 4; c++) {
        float x = acc4[r][c] + b1v[c];
        p += sspf(x) * w2v[c];
        Ss[lr][n0 + c] = sigmf(x) * w2v[c];
      }
      red[lr][tx] = p;
    }
  }
  __syncthreads();
  if (t < 64) {
    int gm = m0 + t;
    if (gm < N_ATOMS) {
      float s = hb2[0];
#pragma unroll
      for (int j = 0; j < 16; j++) s += red[t][j];
      ea[gm] = s;
    }
  }

  float acc[4][8];
#pragma unroll
  for (int r = 0; r < 4; r++)
#pragma unroll
    for (int c = 0; c < 8; c++) acc[r][c] = 0.0f;

  for (int j0 = 0; j0 < 64; j0 += 16) {
#pragma unroll
    for (int it = 0; it < 2; it++) {
      int idx = t + it * 256;
      int n = idx >> 2;
      int jg = (idx & 3) * 4;
      float4 bv = *(const float4*)(hw1 + (size_t)n * 64 + j0 + jg);
      Bs[jg+0][n] = bv.x; Bs[jg+1][n] = bv.y;
      Bs[jg+2][n] = bv.z; Bs[jg+3][n] = bv.w;
    }
    __syncthreads();
#pragma unroll
    for (int kk = 0; kk < 16; kk++) {
      float a[4], b[8];
#pragma unroll
      for (int r = 0; r < 4; r++) a[r] = Ss[ty * 4 + r][j0 + kk];
#pragma unroll
      for (int c = 0; c < 8; c++) b[c] = Bs[kk][tx * 8 + c];
#pragma unroll
      for (int r = 0; r < 4; r++)
#pragma unroll
        for (int c = 0; c < 8; c++) acc[r][c] = fmaf(a[r], b[c], acc[r][c]);
    }
    __syncthreads();
  }

  int n0 = tx * 8;
#pragma unroll
  for (int r = 0; r < 4; r++) {
    int gm = m0 + ty * 4 + r;
    if (gm >= N_ATOMS) continue;
    *(float4*)(gh + (size_t)gm * HD + n0)     = *(float4*)&acc[r][0];
    *(float4*)(gh + (size_t)gm * HD + n0 + 4) = *(float4*)&acc[r][4];
  }
}

// ------------------------------------------------------------------
// per-molecule energy reduction
// ------------------------------------------------------------------
__global__ __launch_bounds__(64) void ered_k(
    const int* __restrict__ batch, const float* __restrict__ ea,
    float* __restrict__ energy)
{
  int m = blockIdx.x;
  int lo = 0, hi = N_ATOMS;
  while (lo < hi) { int mid = (lo + hi) >> 1; if (batch[mid] < m) lo = mid + 1; else hi = mid; }
  int beg = lo;
  lo = beg; hi = N_ATOMS;
  while (lo < hi) { int mid = (lo + hi) >> 1; if (batch[mid] < m + 1) lo = mid + 1; else hi = mid; }
  int end = lo;
  float s = 0.0f;
  for (int i = beg + threadIdx.x; i < end; i += 64) s += ea[i];
#pragma unroll
  for (int off = 32; off > 0; off >>= 1) s += __shfl_down(s, off, 64);
  if (threadIdx.x == 0) energy[m] = s;
}

// ------------------------------------------------------------------
// force gather (other-atom index unpacked from rpk/cpk)
// ------------------------------------------------------------------
__global__ __launch_bounds__(256) void forceg_k(
    const int* __restrict__ rptr, const unsigned* __restrict__ rpk,
    const float* __restrict__ rdist,
    const int* __restrict__ cptr, const unsigned* __restrict__ cpk,
    const float* __restrict__ cdist, const int* __restrict__ cslot,
    const float* __restrict__ ddslot, const float* __restrict__ pos,
    float* __restrict__ force)
{
  int idx = blockIdx.x * 256 + threadIdx.x;
  int a = idx >> 3;
  int g = idx & 7;
  if (a >= N_ATOMS) return;
  float px = pos[3*a+0], py = pos[3*a+1], pz = pos[3*a+2];
  float fx = 0.f, fy = 0.f, fz = 0.f;
  int beg = rptr[a], end = rptr[a+1];
  for (int j = beg + g; j < end; j += 8) {
    int o = rpk[j] & 0xffffu;
    float w = ddslot[j] / rdist[j];
    fx -= w * (px - pos[3*o+0]);
    fy -= w * (py - pos[3*o+1]);
    fz -= w * (pz - pos[3*o+2]);
  }
  beg = cptr[a]; end = cptr[a+1];
  for (int j = beg + g; j < end; j += 8) {
    int o = cpk[j] & 0xffffu;
    float w = ddslot[cslot[j]] / cdist[j];
    fx -= w * (px - pos[3*o+0]);
    fy -= w * (py - pos[3*o+1]);
    fz -= w * (pz - pos[3*o+2]);
  }
#pragma unroll
  for (int off = 4; off > 0; off >>= 1) {
    fx += __shfl_down(fx, off, 8);
    fy += __shfl_down(fy, off, 8);
    fz += __shfl_down(fz, off, 8);
  }
  if (g == 0) {
    force[3*a+0] = fx;
    force[3*a+1] = fy;
    force[3*a+2] = fz;
  }
}

// ------------------------------------------------------------------
// host launch
// ------------------------------------------------------------------
static inline int nblk(int m) { return (m + 63) / 64; }

extern "C" void kernel_launch(void* const* d_in, const int* in_sizes, int n_in,
                              void* d_out, int out_size, void* d_ws, size_t ws_size,
                              hipStream_t stream)
{
  const float* pos   = (const float*)d_in[0];
  const int*   z     = (const int*)d_in[1];
  const int*   batch = (const int*)d_in[2];
  const int*   eidx  = (const int*)d_in[3];
  const float* emb   = (const float*)d_in[4];
  const float* mlp_w1 = (const float*)d_in[5];
  const float* mlp_b1 = (const float*)d_in[6];
  const float* mlp_w2 = (const float*)d_in[7];
  const float* mlp_b2 = (const float*)d_in[8];
  const float* lin1_w = (const float*)d_in[9];
  const float* lin2_w = (const float*)d_in[10];
  const float* lin2_b = (const float*)d_in[11];
  const float* blk_w  = (const float*)d_in[12];
  const float* blk_b  = (const float*)d_in[13];
  const float* hw1 = (const float*)d_in[14];
  const float* hb1 = (const float*)d_in[15];
  const float* hw2 = (const float*)d_in[16];
  const float* hb2 = (const float*)d_in[17];

  float* out = (float*)d_out;          // [NMOL] energies ++ [N,3] forces
  float* ws  = (float*)d_ws;

  const int* row = eidx;
  const int* col = eidx + N_EDGES;

  const size_t NH = (size_t)N_ATOMS * HD;
  size_t o = 0;
  float* ddslot = ws + o; o += N_EDGES;
  int* cptr = (int*)(ws + o); o += N_ATOMS + 1;
  int* rptr = (int*)(ws + o); o += N_ATOMS + 1;
  int* cnt0 = (int*)(ws + o); o += N_ATOMS;      // contiguous with cnt1 for
  int* cnt1 = (int*)(ws + o); o += N_ATOMS;      // a single memset
  int* cur0 = (int*)(ws + o); o += N_ATOMS;
  int* cur1 = (int*)(ws + o); o += N_ATOMS;
  unsigned* cpk = (unsigned*)(ws + o); o += N_EDGES;
  unsigned* rpk = (unsigned*)(ws + o); o += N_EDGES;
  int* cslot = (int*)(ws + o); o += N_EDGES;
  float* cdist = ws + o; o += N_EDGES;
  float* rdist = ws + o; o += N_EDGES;
  o = (o + 3) & ~(size_t)3;                       // 16B align for float4
  float4* ccoef  = (float4*)(ws + o); o += (size_t)4 * N_EDGES;
  float4* rcoefA = (float4*)(ws + o); o += (size_t)4 * N_EDGES;
  float4* rcoefB = (float4*)(ws + o); o += (size_t)4 * N_EDGES;
  // bf16 weights: wt = transposed, wp = plain, mt = transposed mlp weights
  u16* wt = (u16*)(ws + o); o += (size_t)NLAY * 3 * HD * HD / 2;
  u16* wp = (u16*)(ws + o); o += (size_t)NLAY * 3 * HD * HD / 2;
  u16* mt = (u16*)(ws + o); o += (size_t)NLAY * 2 * HD * HD / 2;
  float* hxb[4];   // bf16 (128 u16 per row) -> NH/2 floats each
  for (int i = 0; i < 4; i++) { hxb[i] = ws + o; o += NH / 2; }
  float* svb[4];   // bf16 sigm(V) -> NH/2 floats each
  for (int i = 0; i < 4; i++) { svb[i] = ws + o; o += NH / 2; }
  float* hA  = ws + o; o += NH;
  float* hB  = ws + o; o += NH;
  float* agg = ws + o; o += NH;       // fwd agg / bwd dhx / table temps
  float* g0b = ws + o; o += NH;
  float* g1b = ws + o; o += NH;
  float* dgb = ws + o; o += NH / 2;   // dagg(bf16) / ea / table temps (525k ok)

  // table: bf16 pairs {P*C, (P*C)'}, 1 uint per (node,ch)
  int NT = 1024;
  while (NT > 128) {
    size_t need = o + (size_t)NLAY * (NT + 1) * HD;
    if (need * sizeof(float) <= ws_size) break;
    NT >>= 1;
  }
  const int NN = NT + 1;
  const float hstep = FCUT / (float)NT;
  const float inv_h = (float)NT / FCUT;
  unsigned* T = (unsigned*)(ws + o); o += (size_t)NLAY * NN * HD;

  const int EB = (N_EDGES + 255) / 256;

  hipMemsetAsync(ddslot, 0, N_EDGES * sizeof(float), stream);
  hipMemsetAsync(cnt0, 0, 2 * N_ATOMS * sizeof(int), stream);

  wprep_k<<<(NLAY * 5 * HD * HD + 255) / 256, 256, 0, stream>>>(
      lin1_w, lin2_w, blk_w, mlp_w1, mlp_w2, wt, wp, mt);

  // ---------------- CSR build (both directions, coeffs fused) ----------
  histboth_k<<<EB, 256, 0, stream>>>(row, col, cnt1, cnt0);
  scan2_k<<<2, 256, 0, stream>>>(cnt0, cnt1, cptr, rptr, cur0, cur1);
  scatboth_k<<<EB, 256, 0, stream>>>(pos, row, col, cur0, cur1, cpk, rpk,
                                     cdist, rdist, ccoef, rcoefA, rcoefB,
                                     cslot, inv_h, hstep);

  // ---------------- build filter tables (all 4 layers) ----------------
  {
    const size_t LNH = (size_t)NN * HD;
    float* Anode  = agg;
    float* dAnode = agg + LNH;
    float* t1 = dgb;
    float* u  = g0b;
    float* s  = g1b;
    float* sp = hA;
    nodeA_k<<<((int)LNH + 255) / 256, 256, 0, stream>>>(Anode, dAnode, NN, hstep);
    dim3 gB16((NN + 15) / 16, NLAY, 2);
    tblmm2_k<<<gB16, 256, 0, stream>>>(Anode, dAnode, 0, mt, 32768,
                                       mlp_b1, HD, t1, u, LNH, NN);
    int tot = (int)(NLAY * LNH);
    nodeact_k<<<(tot + 255) / 256, 256, 0, stream>>>(t1, u, s, sp, tot);
    float* P0 = dgb;
    float* D0 = g0b;
    tblmm2_k<<<gB16, 256, 0, stream>>>(s, sp, LNH, mt + 16384, 32768,
                                       mlp_b2, HD, P0, D0, LNH, NN);
    nodecomb_k<<<(tot + 255) / 256, 256, 0, stream>>>(P0, D0, T, NN, hstep);
  }

  h0_k<<<(N_ATOMS * HD + 255) / 256, 256, 0, stream>>>(emb, z, hA);

  const int AB = (N_ATOMS + 3) / 4;
  const int GB = nblk(N_ATOMS);
  const int NB16 = (N_ATOMS + 15) / 16;   // 1250 blocks for no-LDS MFMA GEMMs

  // ---------------- forward ----------------
  float* hcur = hA;
  float* hnxt = hB;
  for (int i = 0; i < NLAY; i++) {
    const u16* l1t = wt + ((size_t)(i*3 + 0) << 14);
    const u16* l2t = wt + ((size_t)(i*3 + 1) << 14);
    const u16* bwt = wt + ((size_t)(i*3 + 2) << 14);
    const float* l2bi = lin2_b + (size_t)i * HD;
    const float* bbi  = blk_b + (size_t)i * HD;
    const unsigned* Tl = T + (size_t)i * NN * HD;

    nmm_hx_k<<<NB16, 256, 0, stream>>>(hcur, l1t, (u16*)hxb[i], N_ATOMS);
    gath_fwd_k<<<AB, 256, 0, stream>>>(cptr, cpk, ccoef, Tl,
                                       (const unsigned*)hxb[i], agg);
    ftail_f_k<<<NB16, 256, 0, stream>>>(agg, l2t, l2bi, bwt, bbi, hcur,
                                        (u16*)svb[i], hnxt, N_ATOMS);
    float* tmp = hcur; hcur = hnxt; hnxt = tmp;
  }

  // ---------------- head (fused) + per-molecule energy ----------------
  // NLAY even -> hcur == hA here
  float* ea = dgb;
  headf_k<<<GB, 256, 0, stream>>>(hcur, hw1, hb1, hw2, hb2, ea, g0b);
  ered_k<<<NMOL, 64, 0, stream>>>(batch, ea, out);

  // ---------------- backward ----------------
  float* gcur = g0b;
  float* gnxt = g1b;
  for (int i = NLAY - 1; i >= 0; i--) {
    const u16* l1p = wp + ((size_t)(i*3 + 0) << 14);
    const u16* l2p = wp + ((size_t)(i*3 + 1) << 14);
    const u16* bwp = wp + ((size_t)(i*3 + 2) << 14);
    const unsigned* Tl = T + (size_t)i * NN * HD;

    bhead_f_k<<<NB16, 256, 0, stream>>>(gcur, bwp, (const u16*)svb[i], l2p,
                                        (u16*)dgb, N_ATOMS);
    gath_bwd_k<<<AB, 256, 0, stream>>>(rptr, rpk, rcoefA, rcoefB, Tl,
                                       (const unsigned*)dgb,
                                       (const unsigned*)hxb[i], agg, ddslot);
    if (i > 0) {
      nmm_bwdT_k<<<NB16, 256, 0, stream>>>(agg, l1p, gcur, gnxt, N_ATOMS);
      float* tmp = gcur; gcur = gnxt; gnxt = tmp;
    }
  }

  forceg_k<<<(N_ATOMS * 8 + 255) / 256, 256, 0, stream>>>(
      rptr, rpk, rdist, cptr, cpk, cdist, cslot, ddslot, pos, out + NMOL);
}

// Round 5
// 834.199 us; speedup vs baseline: 1.4030x; 1.0644x over previous
//
#include <hip/hip_runtime.h>

#define HD 128

constexpr int N_ATOMS = 20000;
constexpr int N_EDGES = 320000;
constexpr int NLAY   = 4;
constexpr int NMOL   = 200;
constexpr float FCUT  = 5.0f;
constexpr float DELTA = FCUT / 127.0f;
constexpr float GCOEFF = -0.5f / (DELTA * DELTA);
constexpr float PI_F  = 3.14159265358979323846f;
constexpr float LN2F  = 0.6931471805599453f;

typedef unsigned short u16;
typedef __attribute__((ext_vector_type(8))) short short8v;
typedef __attribute__((ext_vector_type(4))) float f32x4;

__device__ __forceinline__ float sspf(float x) {
  return fmaxf(x, 0.0f) + log1pf(expf(-fabsf(x))) - LN2F;
}
__device__ __forceinline__ float sigmf(float x) {
  return 1.0f / (1.0f + expf(-x));
}

// bf16 pack/unpack (round-to-nearest-even)
__device__ __forceinline__ unsigned bfpack(float a, float b) {
  unsigned ua = __float_as_uint(a);
  unsigned ub = __float_as_uint(b);
  ua = (ua + 0x7FFFu + ((ua >> 16) & 1u)) >> 16;
  ub = (ub + 0x7FFFu + ((ub >> 16) & 1u)) >> 16;
  return (ub << 16) | ua;
}
__device__ __forceinline__ float bflo(unsigned p) { return __uint_as_float(p << 16); }
__device__ __forceinline__ float bfhi(unsigned p) { return __uint_as_float(p & 0xFFFF0000u); }
__device__ __forceinline__ u16 f2bf(float x) {
  unsigned u = __float_as_uint(x);
  u = (u + 0x7FFFu + ((u >> 16) & 1u)) >> 16;
  return (u16)u;
}
__device__ __forceinline__ float bf2f(u16 b) { return __uint_as_float((unsigned)b << 16); }

// split f32 into hi bf16 (truncate) + lo bf16, packed u32 (hi<<16 | lo)
__device__ __forceinline__ unsigned packhl(float s) {
  unsigned hs = __float_as_uint(s) & 0xffff0000u;
  float lo = s - __uint_as_float(hs);
  return hs | (__float_as_uint(lo) >> 16);
}

// two f32 bit patterns -> hi-pair uint and lo-pair uint (bf16 pairs)
__device__ __forceinline__ unsigned hpair_f32(unsigned a, unsigned b, unsigned& lopair) {
  unsigned ha = a & 0xffff0000u, hb = b & 0xffff0000u;
  float la = __uint_as_float(a) - __uint_as_float(ha);
  float lb = __uint_as_float(b) - __uint_as_float(hb);
  lopair = (__float_as_uint(lb) & 0xffff0000u) | (__float_as_uint(la) >> 16);
  return hb | (ha >> 16);
}

// ------------------------------------------------------------------
// small elementwise kernels
// ------------------------------------------------------------------

__global__ __launch_bounds__(256) void h0_k(
    const float* __restrict__ emb, const int* __restrict__ z,
    float* __restrict__ h0)
{
  int i = blockIdx.x * 256 + threadIdx.x;
  if (i >= N_ATOMS * HD) return;
  int n = i >> 7, k = i & 127;
  h0[i] = emb[z[n] * HD + k];
}

// bf16 weight prep:
//  wsel 0..2 (lin1,lin2,blk): wp = bf16(W) row-major, wt = bf16(W^T)
//  wsel 3..4 (mlp_w1,mlp_w2): mt = bf16(W^T) only
__global__ __launch_bounds__(256) void wprep_k(
    const float* __restrict__ l1, const float* __restrict__ l2,
    const float* __restrict__ bw, const float* __restrict__ mw1,
    const float* __restrict__ mw2,
    u16* __restrict__ wt, u16* __restrict__ wp, u16* __restrict__ mt)
{
  int i = blockIdx.x * 256 + threadIdx.x;
  if (i >= NLAY * 5 * HD * HD) return;
  int e = i & (HD * HD - 1);
  int wl = i >> 14;
  int wsel = wl % 5;
  int lay = wl / 5;
  const float* W;
  if      (wsel == 0) W = l1;
  else if (wsel == 1) W = l2;
  else if (wsel == 2) W = bw;
  else if (wsel == 3) W = mw1;
  else                W = mw2;
  W += (size_t)lay * HD * HD;
  u16 b = f2bf(W[e]);
  int k = e >> 7, n = e & 127;
  if (wsel < 3) {
    size_t base = (size_t)(lay * 3 + wsel) << 14;
    wp[base + e] = b;
    wt[base + (size_t)n * HD + k] = b;
  } else {
    size_t base = (size_t)(lay * 2 + (wsel - 3)) << 14;
    mt[base + (size_t)n * HD + k] = b;
  }
}

// ------------------------------------------------------------------
// CSR build: combined histogram, dual scan, combined scatter+geom+coef
// ------------------------------------------------------------------
__global__ __launch_bounds__(256) void histboth_k(
    const int* __restrict__ row, const int* __restrict__ col,
    int* __restrict__ cntR, int* __restrict__ cntC)
{
  int e = blockIdx.x * 256 + threadIdx.x;
  if (e >= N_EDGES) return;
  atomicAdd(&cntC[col[e]], 1);
  atomicAdd(&cntR[row[e]], 1);
}

// block 0: cnt0 -> cptr,cur0 ; block 1: cnt1 -> rptr,cur1
// register-cached: 20x int4 loads per thread, no dependent-load chains
__global__ __launch_bounds__(256) void scan2_k(
    const int* __restrict__ cnt0, const int* __restrict__ cnt1,
    int* __restrict__ cptr, int* __restrict__ rptr,
    int* __restrict__ cur0, int* __restrict__ cur1)
{
  constexpr int CH = 80;  // 256*80 = 20480 >= 20001; 320 B/thread, 16B-aligned
  __shared__ int part[256];
  const int* cnt = blockIdx.x == 0 ? cnt0 : cnt1;
  int* ptr = blockIdx.x == 0 ? cptr : rptr;
  int* cur = blockIdx.x == 0 ? cur0 : cur1;
  int t = threadIdx.x;
  int base = t * CH;
  int v[CH];
  if (base + CH <= N_ATOMS) {
#pragma unroll
    for (int i = 0; i < CH / 4; i++) {
      int4 q = *(const int4*)(cnt + base + i * 4);
      v[4*i+0] = q.x; v[4*i+1] = q.y; v[4*i+2] = q.z; v[4*i+3] = q.w;
    }
  } else {
#pragma unroll
    for (int i = 0; i < CH; i++)
      v[i] = (base + i < N_ATOMS) ? cnt[base + i] : 0;
  }
  int s = 0;
#pragma unroll
  for (int i = 0; i < CH; i++) s += v[i];
  part[t] = s;
  __syncthreads();
  for (int off = 1; off < 256; off <<= 1) {
    int u = (t >= off) ? part[t - off] : 0;
    __syncthreads();
    part[t] += u;
    __syncthreads();
  }
  int run = part[t] - s;
#pragma unroll
  for (int i = 0; i < CH; i++) {
    int idx = base + i;
    if (idx < N_ATOMS) { ptr[idx] = run; cur[idx] = run; }
    else if (idx == N_ATOMS) ptr[idx] = run;
    run += v[i];
  }
}

// geometry + Hermite coefficients + both-direction CSR scatter, one pass
__global__ __launch_bounds__(256) void scatboth_k(
    const float* __restrict__ pos, const int* __restrict__ row,
    const int* __restrict__ col, int* __restrict__ cur0,
    int* __restrict__ cur1, unsigned* __restrict__ cpk,
    unsigned* __restrict__ rpk, float* __restrict__ cdist,
    float* __restrict__ rdist, float4* __restrict__ ccoef,
    float4* __restrict__ rcoefA, float4* __restrict__ rcoefB,
    int* __restrict__ cslot, float inv_h, float hstep)
{
  int e = blockIdx.x * 256 + threadIdx.x;
  if (e >= N_EDGES) return;
  int r = row[e], c = col[e];
  float dx = pos[3*r+0] - pos[3*c+0];
  float dy = pos[3*r+1] - pos[3*c+1];
  float dz = pos[3*r+2] - pos[3*c+2];
  float d = sqrtf(dx*dx + dy*dy + dz*dz);
  float fi = d * inv_h;
  int i0 = (int)fi;
  float t = fi - (float)i0;
  float t2 = t * t, t3 = t2 * t;
  float a00 = 2.f*t3 - 3.f*t2 + 1.f;
  float a10 = (t3 - 2.f*t2 + t) * hstep;
  float a01 = 3.f*t2 - 2.f*t3;
  float a11 = (t3 - t2) * hstep;
  float b00 = (6.f*t2 - 6.f*t) * inv_h;
  float b10 = 3.f*t2 - 4.f*t + 1.f;
  float b01 = -b00;
  float b11 = 3.f*t2 - 2.f*t;
  int pr = atomicAdd(&cur1[r], 1);
  rpk[pr] = (unsigned)c | ((unsigned)i0 << 16);
  rdist[pr] = d;
  rcoefA[pr] = make_float4(a00, a10, a01, a11);
  rcoefB[pr] = make_float4(b00, b10, b01, b11);
  int pc = atomicAdd(&cur0[c], 1);
  cpk[pc] = (unsigned)r | ((unsigned)i0 << 16);
  cdist[pc] = d;
  ccoef[pc] = make_float4(a00, a10, a01, a11);
  cslot[pc] = pr;
}

// ------------------------------------------------------------------
// table build
// ------------------------------------------------------------------
__global__ __launch_bounds__(256) void nodeA_k(
    float* __restrict__ A, float* __restrict__ dA, int nnode, float hstep)
{
  int i = blockIdx.x * 256 + threadIdx.x;
  if (i >= nnode * HD) return;
  int node = i >> 7, g = i & 127;
  float d = (float)node * hstep;
  float t = d - (float)g * DELTA;
  float a = expf(GCOEFF * t * t);
  A[i] = a;
  dA[i] = a * 2.0f * GCOEFF * t;
}

__global__ __launch_bounds__(256) void nodeact_k(
    const float* __restrict__ t1, const float* __restrict__ u,
    float* __restrict__ s, float* __restrict__ sp, int total)
{
  int i = blockIdx.x * 256 + threadIdx.x;
  if (i >= total) return;
  float x = t1[i];
  s[i] = sspf(x);
  sp[i] = sigmf(x) * u[i];
}

__global__ __launch_bounds__(256) void nodecomb_k(
    const float* __restrict__ P0, const float* __restrict__ D0,
    unsigned* __restrict__ T, int nnode, float hstep)
{
  int i = blockIdx.x * 256 + threadIdx.x;
  int total = NLAY * nnode * HD;
  if (i >= total) return;
  int rem = i % (nnode * HD);
  int node = rem >> 7;
  float d = (float)node * hstep;
  float C  = 0.5f * cosf(d * (PI_F / FCUT)) + 0.5f;
  float Cp = -0.5f * sinf(d * (PI_F / FCUT)) * (PI_F / FCUT);
  float p = P0[i], q = D0[i];
  T[i] = bfpack(p * C, q * C + p * Cp);
}

// ------------------------------------------------------------------
// no-LDS MFMA wave GEMM: wave computes rows [m0,m0+16) x cols
// [wbase,wbase+32) of C = A[M,128] @ B[128,128].
// Bt layout: Bt[n*HD + k] = B[k][n] (bf16).
// ------------------------------------------------------------------
__device__ __forceinline__ void wave_mm(
    const float* __restrict__ Av, const u16* __restrict__ Bt,
    int m0, int wbase, int lc, int lg, int mclamp, f32x4 acc[2])
{
  short8v bfr[4][2];
#pragma unroll
  for (int ks = 0; ks < 4; ++ks)
#pragma unroll
    for (int nt = 0; nt < 2; ++nt)
      bfr[ks][nt] = *(const short8v*)(Bt + (size_t)(wbase + nt*16 + lc) * HD + ks*32 + lg*8);
  int ar = m0 + lc;
  if (ar > mclamp) ar = mclamp;   // row-clamped load; garbage rows never stored
  f32x4 z = {0.f, 0.f, 0.f, 0.f};
  acc[0] = z; acc[1] = z;
#pragma unroll
  for (int ks = 0; ks < 4; ++ks) {
    const float* p = Av + (size_t)ar * HD + ks*32 + lg*8;
    uint4 u0 = *(const uint4*)p;
    uint4 u1 = *(const uint4*)(p + 4);
    unsigned p0l, p1l, p2l, p3l;
    unsigned p0h = hpair_f32(u0.x, u0.y, p0l);
    unsigned p1h = hpair_f32(u0.z, u0.w, p1l);
    unsigned p2h = hpair_f32(u1.x, u1.y, p2l);
    unsigned p3h = hpair_f32(u1.z, u1.w, p3l);
    uint4 hv = make_uint4(p0h, p1h, p2h, p3h);
    uint4 lv = make_uint4(p0l, p1l, p2l, p3l);
    short8v ah = *(short8v*)&hv, al = *(short8v*)&lv;
    acc[0] = __builtin_amdgcn_mfma_f32_16x16x32_bf16(ah, bfr[ks][0], acc[0], 0, 0, 0);
    acc[1] = __builtin_amdgcn_mfma_f32_16x16x32_bf16(ah, bfr[ks][1], acc[1], 0, 0, 0);
    acc[0] = __builtin_amdgcn_mfma_f32_16x16x32_bf16(al, bfr[ks][0], acc[0], 0, 0, 0);
    acc[1] = __builtin_amdgcn_mfma_f32_16x16x32_bf16(al, bfr[ks][1], acc[1], 0, 0, 0);
  }
}

// same, A from LDS tile of packed (hi16|lo16) u32, rows [16][132]
__device__ __forceinline__ void wave_mm_lds(
    const unsigned (*__restrict__ Sl)[132], const u16* __restrict__ Bt,
    int wbase, int lc, int lg, f32x4 acc[2])
{
  short8v bfr[4][2];
#pragma unroll
  for (int ks = 0; ks < 4; ++ks)
#pragma unroll
    for (int nt = 0; nt < 2; ++nt)
      bfr[ks][nt] = *(const short8v*)(Bt + (size_t)(wbase + nt*16 + lc) * HD + ks*32 + lg*8);
  f32x4 z = {0.f, 0.f, 0.f, 0.f};
  acc[0] = z; acc[1] = z;
#pragma unroll
  for (int ks = 0; ks < 4; ++ks) {
    uint4 u0 = *(const uint4*)&Sl[lc][ks*32 + lg*8];
    uint4 u1 = *(const uint4*)&Sl[lc][ks*32 + lg*8 + 4];
    uint4 hv = make_uint4(
      (u0.y & 0xffff0000u) | (u0.x >> 16),
      (u0.w & 0xffff0000u) | (u0.z >> 16),
      (u1.y & 0xffff0000u) | (u1.x >> 16),
      (u1.w & 0xffff0000u) | (u1.z >> 16));
    uint4 lv = make_uint4(
      (u0.y << 16) | (u0.x & 0xffffu),
      (u0.w << 16) | (u0.z & 0xffffu),
      (u1.y << 16) | (u1.x & 0xffffu),
      (u1.w << 16) | (u1.z & 0xffffu));
    short8v ah = *(short8v*)&hv, al = *(short8v*)&lv;
    acc[0] = __builtin_amdgcn_mfma_f32_16x16x32_bf16(ah, bfr[ks][0], acc[0], 0, 0, 0);
    acc[1] = __builtin_amdgcn_mfma_f32_16x16x32_bf16(ah, bfr[ks][1], acc[1], 0, 0, 0);
    acc[0] = __builtin_amdgcn_mfma_f32_16x16x32_bf16(al, bfr[ks][0], acc[0], 0, 0, 0);
    acc[1] = __builtin_amdgcn_mfma_f32_16x16x32_bf16(al, bfr[ks][1], acc[1], 0, 0, 0);
  }
}

// hx = h @ W  (Bt = W^T bf16), output u16 bf16  (layer 0 only)
__global__ __launch_bounds__(256) void nmm_hx_k(
    const float* __restrict__ h, const u16* __restrict__ Bt,
    u16* __restrict__ hx, int M)
{
  int t = threadIdx.x, lane = t & 63;
  int lc = lane & 15, lg = lane >> 4;
  int wbase = (t >> 6) * 32;
  int m0 = blockIdx.x * 16;
  f32x4 acc[2];
  wave_mm(h, Bt, m0, wbase, lc, lg, M - 1, acc);
#pragma unroll
  for (int nt = 0; nt < 2; ++nt) {
    int ccol = wbase + nt*16 + lc;
#pragma unroll
    for (int j = 0; j < 4; ++j) {
      int grow = m0 + lg*4 + j;
      if (grow < M) hx[(size_t)grow * HD + ccol] = f2bf(acc[nt][j]);
    }
  }
}

// C = A @ W^T + addin  (Bp = W bf16 row-major), fp32 out
__global__ __launch_bounds__(256) void nmm_bwdT_k(
    const float* __restrict__ A, const u16* __restrict__ Bp,
    const float* __restrict__ addin, float* __restrict__ C, int M)
{
  int t = threadIdx.x, lane = t & 63;
  int lc = lane & 15, lg = lane >> 4;
  int wbase = (t >> 6) * 32;
  int m0 = blockIdx.x * 16;
  f32x4 acc[2];
  wave_mm(A, Bp, m0, wbase, lc, lg, M - 1, acc);
#pragma unroll
  for (int nt = 0; nt < 2; ++nt) {
    int ccol = wbase + nt*16 + lc;
#pragma unroll
    for (int j = 0; j < 4; ++j) {
      int grow = m0 + lg*4 + j;
      if (grow < M)
        C[(size_t)grow * HD + ccol] = acc[nt][j] + addin[(size_t)grow * HD + ccol];
    }
  }
}

// fused fwd tail: V = agg@l2 + l2b; svb = bf16(sigm(V));
// hout = h + ssp(V)@bw + bb; optional hxn = bf16(hout @ l1next)
__global__ __launch_bounds__(256) void ftail_f_k(
    const float* __restrict__ agg, const u16* __restrict__ l2t,
    const float* __restrict__ l2b, const u16* __restrict__ bwt,
    const float* __restrict__ bb, const float* __restrict__ h,
    u16* __restrict__ svb, float* __restrict__ hout,
    const u16* __restrict__ l1n, u16* __restrict__ hxn, int M)
{
  __shared__ unsigned Sl[16][132];
  int t = threadIdx.x, lane = t & 63;
  int lc = lane & 15, lg = lane >> 4;
  int wbase = (t >> 6) * 32;
  int m0 = blockIdx.x * 16;
  f32x4 acc[2];
  wave_mm(agg, l2t, m0, wbase, lc, lg, M - 1, acc);
#pragma unroll
  for (int nt = 0; nt < 2; ++nt) {
    int ccol = wbase + nt*16 + lc;
    float bv = l2b[ccol];
#pragma unroll
    for (int j = 0; j < 4; ++j) {
      int lrow = lg*4 + j;
      int grow = m0 + lrow;
      float s = 0.0f;
      if (grow < M) {
        float x = acc[nt][j] + bv;
        svb[(size_t)grow * HD + ccol] = f2bf(sigmf(x));
        s = sspf(x);
      }
      Sl[lrow][ccol] = packhl(s);
    }
  }
  __syncthreads();
  wave_mm_lds(Sl, bwt, wbase, lc, lg, acc);

  float ho[2][4];
#pragma unroll
  for (int nt = 0; nt < 2; ++nt) {
    int ccol = wbase + nt*16 + lc;
    float bv = bb[ccol];
#pragma unroll
    for (int j = 0; j < 4; ++j) {
      int grow = m0 + lg*4 + j;
      float x = 0.0f;
      if (grow < M) {
        x = acc[nt][j] + bv + h[(size_t)grow * HD + ccol];
        hout[(size_t)grow * HD + ccol] = x;
      }
      ho[nt][j] = x;
    }
  }
  if (l1n) {
    __syncthreads();   // all waves done reading Sl (bw pass)
#pragma unroll
    for (int nt = 0; nt < 2; ++nt) {
      int ccol = wbase + nt*16 + lc;
#pragma unroll
      for (int j = 0; j < 4; ++j)
        Sl[lg*4 + j][ccol] = packhl(ho[nt][j]);
    }
    __syncthreads();
    wave_mm_lds(Sl, l1n, wbase, lc, lg, acc);
#pragma unroll
    for (int nt = 0; nt < 2; ++nt) {
      int ccol = wbase + nt*16 + lc;
#pragma unroll
      for (int j = 0; j < 4; ++j) {
        int grow = m0 + lg*4 + j;
        if (grow < M) hxn[(size_t)grow * HD + ccol] = f2bf(acc[nt][j]);
      }
    }
  }
}

// fused bwd head: dv = (g@bw^T)*sigm(V) (from svb); dagg = dv@l2^T (bf16)
__global__ __launch_bounds__(256) void bhead_f_k(
    const float* __restrict__ g, const u16* __restrict__ bwp,
    const u16* __restrict__ svb, const u16* __restrict__ l2p,
    u16* __restrict__ dagg, int M)
{
  __shared__ unsigned Sl[16][132];
  int t = threadIdx.x, lane = t & 63;
  int lc = lane & 15, lg = lane >> 4;
  int wbase = (t >> 6) * 32;
  int m0 = blockIdx.x * 16;
  f32x4 acc[2];
  wave_mm(g, bwp, m0, wbase, lc, lg, M - 1, acc);
#pragma unroll
  for (int nt = 0; nt < 2; ++nt) {
    int ccol = wbase + nt*16 + lc;
#pragma unroll
    for (int j = 0; j < 4; ++j) {
      int lrow = lg*4 + j;
      int grow = m0 + lrow;
      float dv = 0.0f;
      if (grow < M)
        dv = acc[nt][j] * bf2f(svb[(size_t)grow * HD + ccol]);
      Sl[lrow][ccol] = packhl(dv);
    }
  }
  __syncthreads();
  wave_mm_lds(Sl, l2p, wbase, lc, lg, acc);
#pragma unroll
  for (int nt = 0; nt < 2; ++nt) {
    int ccol = wbase + nt*16 + lc;
#pragma unroll
    for (int j = 0; j < 4; ++j) {
      int grow = m0 + lg*4 + j;
      if (grow < M) dagg[(size_t)grow * HD + ccol] = f2bf(acc[nt][j]);
    }
  }
}

// batched table-build GEMM; blockIdx.z selects (A0,bias0,C0) or (A1,null,C1)
__global__ __launch_bounds__(256) void tblmm2_k(
    const float* __restrict__ A0, const float* __restrict__ A1, size_t astride,
    const u16* __restrict__ Bt, size_t bstride,
    const float* __restrict__ bias0, size_t biasstride,
    float* __restrict__ C0, float* __restrict__ C1, size_t cstride, int M)
{
  int l = blockIdx.y;
  int zz = blockIdx.z;
  const float* A = (zz ? A1 : A0) + (size_t)l * astride;
  const u16* B = Bt + (size_t)l * bstride;
  const float* bias = zz ? nullptr : (bias0 ? bias0 + (size_t)l * biasstride : nullptr);
  float* C = (zz ? C1 : C0) + (size_t)l * cstride;
  int t = threadIdx.x, lane = t & 63;
  int lc = lane & 15, lg = lane >> 4;
  int wbase = (t >> 6) * 32;
  int m0 = blockIdx.x * 16;
  f32x4 acc[2];
  wave_mm(A, B, m0, wbase, lc, lg, M - 1, acc);
#pragma unroll
  for (int nt = 0; nt < 2; ++nt) {
    int ccol = wbase + nt*16 + lc;
    float bv = bias ? bias[ccol] : 0.0f;
#pragma unroll
    for (int j = 0; j < 4; ++j) {
      int grow = m0 + lg*4 + j;
      if (grow < M) C[(size_t)grow * HD + ccol] = acc[nt][j] + bv;
    }
  }
}

// ------------------------------------------------------------------
// forward gather: agg[a] = sum_in hx[src] * P(d); precomputed coeffs
// ------------------------------------------------------------------
__global__ __launch_bounds__(256) void gath_fwd_k(
    const int* __restrict__ cptr, const unsigned* __restrict__ cpk,
    const float4* __restrict__ ccoef, const unsigned* __restrict__ T,
    const unsigned* __restrict__ hx, float* __restrict__ agg)
{
  int a = blockIdx.x * 4 + (threadIdx.x >> 6);
  if (a >= N_ATOMS) return;
  int half = (threadIdx.x >> 5) & 1;
  int l32 = threadIdx.x & 31;
  int ch = l32 * 4;
  int beg = cptr[a], end = cptr[a + 1];
  float s0 = 0.f, s1 = 0.f, s2 = 0.f, s3 = 0.f;
#pragma unroll 2
  for (int j = beg + half; j < end; j += 2) {
    unsigned pk = cpk[j];
    float4 cf = ccoef[j];
    int other = pk & 0xffffu;
    const unsigned* tp = T + (size_t)(pk >> 16) * HD + ch;
    uint4 q0 = *(const uint4*)(tp);
    uint4 q1 = *(const uint4*)(tp + HD);
    uint2 hp = *(const uint2*)(hx + (size_t)other * 64 + l32 * 2);
    float v0 = cf.x*bflo(q0.x) + cf.y*bfhi(q0.x) + cf.z*bflo(q1.x) + cf.w*bfhi(q1.x);
    float v1 = cf.x*bflo(q0.y) + cf.y*bfhi(q0.y) + cf.z*bflo(q1.y) + cf.w*bfhi(q1.y);
    float v2 = cf.x*bflo(q0.z) + cf.y*bfhi(q0.z) + cf.z*bflo(q1.z) + cf.w*bfhi(q1.z);
    float v3 = cf.x*bflo(q0.w) + cf.y*bfhi(q0.w) + cf.z*bflo(q1.w) + cf.w*bfhi(q1.w);
    s0 = fmaf(bflo(hp.x), v0, s0);
    s1 = fmaf(bfhi(hp.x), v1, s1);
    s2 = fmaf(bflo(hp.y), v2, s2);
    s3 = fmaf(bfhi(hp.y), v3, s3);
  }
  s0 += __shfl_xor(s0, 32, 64);
  s1 += __shfl_xor(s1, 32, 64);
  s2 += __shfl_xor(s2, 32, 64);
  s3 += __shfl_xor(s3, 32, 64);
  if (half == 0)
    *(float4*)(agg + (size_t)a * HD + ch) = make_float4(s0, s1, s2, s3);
}

// ------------------------------------------------------------------
// backward gather: dhx + per-edge ddslot (write on first layer, else +=)
// ------------------------------------------------------------------
__global__ __launch_bounds__(256) void gath_bwd_k(
    const int* __restrict__ rptr, const unsigned* __restrict__ rpk,
    const float4* __restrict__ rcoefA, const float4* __restrict__ rcoefB,
    const unsigned* __restrict__ T, const unsigned* __restrict__ dagg,
    const unsigned* __restrict__ hx, float* __restrict__ dhx,
    float* __restrict__ ddslot, int accum)
{
  int a = blockIdx.x * 4 + (threadIdx.x >> 6);
  if (a >= N_ATOMS) return;
  int half = (threadIdx.x >> 5) & 1;
  int l32 = threadIdx.x & 31;
  int ch = l32 * 4;
  int beg = rptr[a], end = rptr[a + 1];
  uint2 hp = *(const uint2*)(hx + (size_t)a * 64 + l32 * 2);
  float h0 = bflo(hp.x), h1 = bfhi(hp.x), h2 = bflo(hp.y), h3 = bfhi(hp.y);
  float s0 = 0.f, s1 = 0.f, s2 = 0.f, s3 = 0.f;
#pragma unroll 2
  for (int j = beg + half; j < end; j += 2) {
    unsigned pk = rpk[j];
    float4 ca = rcoefA[j];
    float4 cb = rcoefB[j];
    int other = pk & 0xffffu;
    const unsigned* tp = T + (size_t)(pk >> 16) * HD + ch;
    uint4 q0 = *(const uint4*)(tp);
    uint4 q1 = *(const uint4*)(tp + HD);
    uint2 dp = *(const uint2*)(dagg + (size_t)other * 64 + l32 * 2);
    float da0 = bflo(dp.x), da1 = bfhi(dp.x), da2 = bflo(dp.y), da3 = bfhi(dp.y);
    float x0l = bflo(q0.x), x0h = bfhi(q0.x), y0l = bflo(q1.x), y0h = bfhi(q1.x);
    float x1l = bflo(q0.y), x1h = bfhi(q0.y), y1l = bflo(q1.y), y1h = bfhi(q1.y);
    float x2l = bflo(q0.z), x2h = bfhi(q0.z), y2l = bflo(q1.z), y2h = bfhi(q1.z);
    float x3l = bflo(q0.w), x3h = bfhi(q0.w), y3l = bflo(q1.w), y3h = bfhi(q1.w);
    float v0 = ca.x*x0l + ca.y*x0h + ca.z*y0l + ca.w*y0h;
    float v1 = ca.x*x1l + ca.y*x1h + ca.z*y1l + ca.w*y1h;
    float v2 = ca.x*x2l + ca.y*x2h + ca.z*y2l + ca.w*y2h;
    float v3 = ca.x*x3l + ca.y*x3h + ca.z*y3l + ca.w*y3h;
    float g0 = cb.x*x0l + cb.y*x0h + cb.z*y0l + cb.w*y0h;
    float g1 = cb.x*x1l + cb.y*x1h + cb.z*y1l + cb.w*y1h;
    float g2 = cb.x*x2l + cb.y*x2h + cb.z*y2l + cb.w*y2h;
    float g3 = cb.x*x3l + cb.y*x3h + cb.z*y3l + cb.w*y3h;
    s0 = fmaf(da0, v0, s0);
    s1 = fmaf(da1, v1, s1);
    s2 = fmaf(da2, v2, s2);
    s3 = fmaf(da3, v3, s3);
    float dot = da0*h0*g0 + da1*h1*g1 + da2*h2*g2 + da3*h3*g3;
#pragma unroll
    for (int off = 16; off > 0; off >>= 1) dot += __shfl_down(dot, off, 32);
    if (l32 == 0) ddslot[j] = accum ? (ddslot[j] + dot) : dot;
  }
  s0 += __shfl_xor(s0, 32, 64);
  s1 += __shfl_xor(s1, 32, 64);
  s2 += __shfl_xor(s2, 32, 64);
  s3 += __shfl_xor(s3, 32, 64);
  if (half == 0)
    *(float4*)(dhx + (size_t)a * HD + ch) = make_float4(s0, s1, s2, s3);
}

// ------------------------------------------------------------------
// fused head: s = h4@hw1 + hb1; ea[a] = ssp(s)@hw2 + hb2;
// gh = (sigm(s)*hw2) @ hw1^T
// ------------------------------------------------------------------
__global__ __launch_bounds__(256) void headf_k(
    const float* __restrict__ h4, const float* __restrict__ hw1,
    const float* __restrict__ hb1, const float* __restrict__ hw2,
    const float* __restrict__ hb2, float* __restrict__ ea,
    float* __restrict__ gh)
{
  __shared__ float As[16][68];
  __shared__ float Bs[16][132];
  __shared__ float Ss[64][68];
  __shared__ float red[64][17];
  int t = threadIdx.x;
  int tx = t & 15, ty = t >> 4;
  int m0 = blockIdx.x * 64;

  float acc4[4][4];
#pragma unroll
  for (int r = 0; r < 4; r++)
#pragma unroll
    for (int c = 0; c < 4; c++) acc4[r][c] = 0.0f;

  for (int k0 = 0; k0 < HD; k0 += 16) {
    {
      int rrow = t >> 2;
      int kg = (t & 3) * 4;
      int gm = m0 + rrow;
      float4 av = make_float4(0.f, 0.f, 0.f, 0.f);
      if (gm < N_ATOMS) av = *(const float4*)(h4 + (size_t)gm * HD + k0 + kg);
      As[kg+0][rrow] = av.x; As[kg+1][rrow] = av.y;
      As[kg+2][rrow] = av.z; As[kg+3][rrow] = av.w;
    }
    if (t < 256) {
      int kk = t >> 4;
      int n4 = (t & 15) * 4;
      float4 bv = *(const float4*)(hw1 + (size_t)(k0 + kk) * 64 + n4);
      *(float4*)&Bs[kk][n4] = bv;
    }
    __syncthreads();
#pragma unroll
    for (int kk = 0; kk < 16; kk++) {
      float a[4], b[4];
#pragma unroll
      for (int r = 0; r < 4; r++) a[r] = As[kk][ty * 4 + r];
#pragma unroll
      for (int c = 0; c < 4; c++) b[c] = Bs[kk][tx * 4 + c];
#pragma unroll
      for (int r = 0; r < 4; r++)
#pragma unroll
        for (int c = 0; c < 4; c++) acc4[r][c] = fmaf(a[r], b[c], acc4[r][c]);
    }
    __syncthreads();
  }

  {
    int n0 = tx * 4;
    float b1v[4], w2v[4];
#pragma unroll
    for (int c = 0; c < 4; c++) { b1v[c] = hb1[n0 + c]; w2v[c] = hw2[n0 + c]; }
#pragma unroll
    for (int r = 0; r < 4; r++) {
      int lr = ty * 4 + r;
      float p = 0.0f;
#pragma unroll
      for (int c = 0; c < 4; c++) {
        float x = acc4[r][c] + b1v[c];
        p += sspf(x) * w2v[c];
        Ss[lr][n0 + c] = sigmf(x) * w2v[c];
      }
      red[lr][tx] = p;
    }
  }
  __syncthreads();
  if (t < 64) {
    int gm = m0 + t;
    if (gm < N_ATOMS) {
      float s = hb2[0];
#pragma unroll
      for (int j = 0; j < 16; j++) s += red[t][j];
      ea[gm] = s;
    }
  }

  float acc[4][8];
#pragma unroll
  for (int r = 0; r < 4; r++)
#pragma unroll
    for (int c = 0; c < 8; c++) acc[r][c] = 0.0f;

  for (int j0 = 0; j0 < 64; j0 += 16) {
#pragma unroll
    for (int it = 0; it < 2; it++) {
      int idx = t + it * 256;
      int n = idx >> 2;
      int jg = (idx & 3) * 4;
      float4 bv = *(const float4*)(hw1 + (size_t)n * 64 + j0 + jg);
      Bs[jg+0][n] = bv.x; Bs[jg+1][n] = bv.y;
      Bs[jg+2][n] = bv.z; Bs[jg+3][n] = bv.w;
    }
    __syncthreads();
#pragma unroll
    for (int kk = 0; kk < 16; kk++) {
      float a[4], b[8];
#pragma unroll
      for (int r = 0; r < 4; r++) a[r] = Ss[ty * 4 + r][j0 + kk];
#pragma unroll
      for (int c = 0; c < 8; c++) b[c] = Bs[kk][tx * 8 + c];
#pragma unroll
      for (int r = 0; r < 4; r++)
#pragma unroll
        for (int c = 0; c < 8; c++) acc[r][c] = fmaf(a[r], b[c], acc[r][c]);
    }
    __syncthreads();
  }

  int n0 = tx * 8;
#pragma unroll
  for (int r = 0; r < 4; r++) {
    int gm = m0 + ty * 4 + r;
    if (gm >= N_ATOMS) continue;
    *(float4*)(gh + (size_t)gm * HD + n0)     = *(float4*)&acc[r][0];
    *(float4*)(gh + (size_t)gm * HD + n0 + 4) = *(float4*)&acc[r][4];
  }
}

// ------------------------------------------------------------------
// per-molecule energy reduction
// ------------------------------------------------------------------
__global__ __launch_bounds__(64) void ered_k(
    const int* __restrict__ batch, const float* __restrict__ ea,
    float* __restrict__ energy)
{
  int m = blockIdx.x;
  int lo = 0, hi = N_ATOMS;
  while (lo < hi) { int mid = (lo + hi) >> 1; if (batch[mid] < m) lo = mid + 1; else hi = mid; }
  int beg = lo;
  lo = beg; hi = N_ATOMS;
  while (lo < hi) { int mid = (lo + hi) >> 1; if (batch[mid] < m + 1) lo = mid + 1; else hi = mid; }
  int end = lo;
  float s = 0.0f;
  for (int i = beg + threadIdx.x; i < end; i += 64) s += ea[i];
#pragma unroll
  for (int off = 32; off > 0; off >>= 1) s += __shfl_down(s, off, 64);
  if (threadIdx.x == 0) energy[m] = s;
}

// ------------------------------------------------------------------
// force gather (other-atom index unpacked from rpk/cpk)
// ------------------------------------------------------------------
__global__ __launch_bounds__(256) void forceg_k(
    const int* __restrict__ rptr, const unsigned* __restrict__ rpk,
    const float* __restrict__ rdist,
    const int* __restrict__ cptr, const unsigned* __restrict__ cpk,
    const float* __restrict__ cdist, const int* __restrict__ cslot,
    const float* __restrict__ ddslot, const float* __restrict__ pos,
    float* __restrict__ force)
{
  int idx = blockIdx.x * 256 + threadIdx.x;
  int a = idx >> 3;
  int g = idx & 7;
  if (a >= N_ATOMS) return;
  float px = pos[3*a+0], py = pos[3*a+1], pz = pos[3*a+2];
  float fx = 0.f, fy = 0.f, fz = 0.f;
  int beg = rptr[a], end = rptr[a+1];
  for (int j = beg + g; j < end; j += 8) {
    int o = rpk[j] & 0xffffu;
    float w = ddslot[j] / rdist[j];
    fx -= w * (px - pos[3*o+0]);
    fy -= w * (py - pos[3*o+1]);
    fz -= w * (pz - pos[3*o+2]);
  }
  beg = cptr[a]; end = cptr[a+1];
  for (int j = beg + g; j < end; j += 8) {
    int o = cpk[j] & 0xffffu;
    float w = ddslot[cslot[j]] / cdist[j];
    fx -= w * (px - pos[3*o+0]);
    fy -= w * (py - pos[3*o+1]);
    fz -= w * (pz - pos[3*o+2]);
  }
#pragma unroll
  for (int off = 4; off > 0; off >>= 1) {
    fx += __shfl_down(fx, off, 8);
    fy += __shfl_down(fy, off, 8);
    fz += __shfl_down(fz, off, 8);
  }
  if (g == 0) {
    force[3*a+0] = fx;
    force[3*a+1] = fy;
    force[3*a+2] = fz;
  }
}

// ------------------------------------------------------------------
// host launch
// ------------------------------------------------------------------
static inline int nblk(int m) { return (m + 63) / 64; }

extern "C" void kernel_launch(void* const* d_in, const int* in_sizes, int n_in,
                              void* d_out, int out_size, void* d_ws, size_t ws_size,
                              hipStream_t stream)
{
  const float* pos   = (const float*)d_in[0];
  const int*   z     = (const int*)d_in[1];
  const int*   batch = (const int*)d_in[2];
  const int*   eidx  = (const int*)d_in[3];
  const float* emb   = (const float*)d_in[4];
  const float* mlp_w1 = (const float*)d_in[5];
  const float* mlp_b1 = (const float*)d_in[6];
  const float* mlp_w2 = (const float*)d_in[7];
  const float* mlp_b2 = (const float*)d_in[8];
  const float* lin1_w = (const float*)d_in[9];
  const float* lin2_w = (const float*)d_in[10];
  const float* lin2_b = (const float*)d_in[11];
  const float* blk_w  = (const float*)d_in[12];
  const float* blk_b  = (const float*)d_in[13];
  const float* hw1 = (const float*)d_in[14];
  const float* hb1 = (const float*)d_in[15];
  const float* hw2 = (const float*)d_in[16];
  const float* hb2 = (const float*)d_in[17];

  float* out = (float*)d_out;          // [NMOL] energies ++ [N,3] forces
  float* ws  = (float*)d_ws;

  const int* row = eidx;
  const int* col = eidx + N_EDGES;

  const size_t NH = (size_t)N_ATOMS * HD;
  size_t o = 0;
  float* ddslot = ws + o; o += N_EDGES;
  int* cptr = (int*)(ws + o); o += N_ATOMS + 1;
  int* rptr = (int*)(ws + o); o += N_ATOMS + 1;
  int* cnt0 = (int*)(ws + o); o += N_ATOMS;      // contiguous with cnt1 for
  int* cnt1 = (int*)(ws + o); o += N_ATOMS;      // a single memset
  int* cur0 = (int*)(ws + o); o += N_ATOMS;
  int* cur1 = (int*)(ws + o); o += N_ATOMS;
  unsigned* cpk = (unsigned*)(ws + o); o += N_EDGES;
  unsigned* rpk = (unsigned*)(ws + o); o += N_EDGES;
  int* cslot = (int*)(ws + o); o += N_EDGES;
  float* cdist = ws + o; o += N_EDGES;
  float* rdist = ws + o; o += N_EDGES;
  o = (o + 3) & ~(size_t)3;                       // 16B align for float4
  float4* ccoef  = (float4*)(ws + o); o += (size_t)4 * N_EDGES;
  float4* rcoefA = (float4*)(ws + o); o += (size_t)4 * N_EDGES;
  float4* rcoefB = (float4*)(ws + o); o += (size_t)4 * N_EDGES;
  // bf16 weights: wt = transposed, wp = plain, mt = transposed mlp weights
  u16* wt = (u16*)(ws + o); o += (size_t)NLAY * 3 * HD * HD / 2;
  u16* wp = (u16*)(ws + o); o += (size_t)NLAY * 3 * HD * HD / 2;
  u16* mt = (u16*)(ws + o); o += (size_t)NLAY * 2 * HD * HD / 2;
  float* hxb[4];   // bf16 (128 u16 per row) -> NH/2 floats each
  for (int i = 0; i < 4; i++) { hxb[i] = ws + o; o += NH / 2; }
  float* svb[4];   // bf16 sigm(V) -> NH/2 floats each
  for (int i = 0; i < 4; i++) { svb[i] = ws + o; o += NH / 2; }
  float* hA  = ws + o; o += NH;
  float* hB  = ws + o; o += NH;
  float* agg = ws + o; o += NH;       // fwd agg / bwd dhx / table temps
  float* g0b = ws + o; o += NH;
  float* g1b = ws + o; o += NH;
  float* dgb = ws + o; o += NH / 2;   // dagg(bf16) / ea / table temps

  // table: bf16 pairs {P*C, (P*C)'}, 1 uint per (node,ch)
  int NT = 1024;
  while (NT > 128) {
    size_t need = o + (size_t)NLAY * (NT + 1) * HD;
    if (need * sizeof(float) <= ws_size) break;
    NT >>= 1;
  }
  const int NN = NT + 1;
  const float hstep = FCUT / (float)NT;
  const float inv_h = (float)NT / FCUT;
  unsigned* T = (unsigned*)(ws + o); o += (size_t)NLAY * NN * HD;

  const int EB = (N_EDGES + 255) / 256;

  hipMemsetAsync(cnt0, 0, 2 * N_ATOMS * sizeof(int), stream);

  wprep_k<<<(NLAY * 5 * HD * HD + 255) / 256, 256, 0, stream>>>(
      lin1_w, lin2_w, blk_w, mlp_w1, mlp_w2, wt, wp, mt);

  // ---------------- CSR build (both directions, coeffs fused) ----------
  histboth_k<<<EB, 256, 0, stream>>>(row, col, cnt1, cnt0);
  scan2_k<<<2, 256, 0, stream>>>(cnt0, cnt1, cptr, rptr, cur0, cur1);
  scatboth_k<<<EB, 256, 0, stream>>>(pos, row, col, cur0, cur1, cpk, rpk,
                                     cdist, rdist, ccoef, rcoefA, rcoefB,
                                     cslot, inv_h, hstep);

  // ---------------- build filter tables (all 4 layers) ----------------
  {
    const size_t LNH = (size_t)NN * HD;
    float* Anode  = agg;
    float* dAnode = agg + LNH;
    float* t1 = dgb;
    float* u  = g0b;
    float* s  = g1b;
    float* sp = hA;
    nodeA_k<<<((int)LNH + 255) / 256, 256, 0, stream>>>(Anode, dAnode, NN, hstep);
    dim3 gB16((NN + 15) / 16, NLAY, 2);
    tblmm2_k<<<gB16, 256, 0, stream>>>(Anode, dAnode, 0, mt, 32768,
                                       mlp_b1, HD, t1, u, LNH, NN);
    int tot = (int)(NLAY * LNH);
    nodeact_k<<<(tot + 255) / 256, 256, 0, stream>>>(t1, u, s, sp, tot);
    float* P0 = dgb;
    float* D0 = g0b;
    tblmm2_k<<<gB16, 256, 0, stream>>>(s, sp, LNH, mt + 16384, 32768,
                                       mlp_b2, HD, P0, D0, LNH, NN);
    nodecomb_k<<<(tot + 255) / 256, 256, 0, stream>>>(P0, D0, T, NN, hstep);
  }

  h0_k<<<(N_ATOMS * HD + 255) / 256, 256, 0, stream>>>(emb, z, hA);

  const int AB = (N_ATOMS + 3) / 4;
  const int GB = nblk(N_ATOMS);
  const int NB16 = (N_ATOMS + 15) / 16;   // 1250 blocks for no-LDS MFMA GEMMs

  // ---------------- forward ----------------
  float* hcur = hA;
  float* hnxt = hB;
  nmm_hx_k<<<NB16, 256, 0, stream>>>(hcur, wt, (u16*)hxb[0], N_ATOMS);
  for (int i = 0; i < NLAY; i++) {
    const u16* l2t = wt + ((size_t)(i*3 + 1) << 14);
    const u16* bwt = wt + ((size_t)(i*3 + 2) << 14);
    const u16* l1n = (i < NLAY - 1) ? wt + ((size_t)((i+1)*3 + 0) << 14) : nullptr;
    u16* hxn = (i < NLAY - 1) ? (u16*)hxb[i+1] : nullptr;
    const float* l2bi = lin2_b + (size_t)i * HD;
    const float* bbi  = blk_b + (size_t)i * HD;
    const unsigned* Tl = T + (size_t)i * NN * HD;

    gath_fwd_k<<<AB, 256, 0, stream>>>(cptr, cpk, ccoef, Tl,
                                       (const unsigned*)hxb[i], agg);
    ftail_f_k<<<NB16, 256, 0, stream>>>(agg, l2t, l2bi, bwt, bbi, hcur,
                                        (u16*)svb[i], hnxt, l1n, hxn, N_ATOMS);
    float* tmp = hcur; hcur = hnxt; hnxt = tmp;
  }

  // ---------------- head (fused) + per-molecule energy ----------------
  // NLAY even -> hcur == hA here
  float* ea = dgb;
  headf_k<<<GB, 256, 0, stream>>>(hcur, hw1, hb1, hw2, hb2, ea, g0b);
  ered_k<<<NMOL, 64, 0, stream>>>(batch, ea, out);

  // ---------------- backward ----------------
  float* gcur = g0b;
  float* gnxt = g1b;
  for (int i = NLAY - 1; i >= 0; i--) {
    const u16* l1p = wp + ((size_t)(i*3 + 0) << 14);
    const u16* l2p = wp + ((size_t)(i*3 + 1) << 14);
    const u16* bwp = wp + ((size_t)(i*3 + 2) << 14);
    const unsigned* Tl = T + (size_t)i * NN * HD;

    bhead_f_k<<<NB16, 256, 0, stream>>>(gcur, bwp, (const u16*)svb[i], l2p,
                                        (u16*)dgb, N_ATOMS);
    gath_bwd_k<<<AB, 256, 0, stream>>>(rptr, rpk, rcoefA, rcoefB, Tl,
                                       (const unsigned*)dgb,
                                       (const unsigned*)hxb[i], agg, ddslot,
                                       i != NLAY - 1);
    if (i > 0) {
      nmm_bwdT_k<<<NB16, 256, 0, stream>>>(agg, l1p, gcur, gnxt, N_ATOMS);
      float* tmp = gcur; gcur = gnxt; gnxt = tmp;
    }
  }

  forceg_k<<<(N_ATOMS * 8 + 255) / 256, 256, 0, stream>>>(
      rptr, rpk, rdist, cptr, cpk, cdist, cslot, ddslot, pos, out + NMOL);
}